// Round 14
// baseline (759.968 us; speedup 1.0000x reference)
//
#include <hip/hip_runtime.h>
#include <math.h>

#define Nn 50000
#define Ee 800000
#define Bb 8
#define ROUNDS 4
#define KWVB 512            // kwv partial blocks (2/CU)
#define SCB 196             // scan blocks (196*256 = 50176 >= Nn)
#define AP 40               // MFMA LDS row stride in shorts (32 k + 8 pad)
#define HP 132              // kwv fp32 h_s row stride (128 + 4 pad)
#define KS 40               // kwv bf16 transposed row stride in shorts
#define NSL 8               // dst slices (1 per XCD)
#define SLB 32              // blocks per slice
#define SLN 6250            // Nn / NSL

typedef __attribute__((ext_vector_type(8))) short bf16x8;
typedef __attribute__((ext_vector_type(4))) float f32x4;

__device__ inline short f2bf(float f) {
  union { float f; unsigned u; } v; v.f = f;
  unsigned r = v.u + 0x7fff + ((v.u >> 16) & 1);  // RNE
  return (short)(r >> 16);
}
__device__ inline float bf2f(short s) {
  union { float f; unsigned u; } v; v.u = ((unsigned)(unsigned short)s) << 16;
  return v.f;
}

// ---------------------------------------------------------------- encode + fused segmean
__global__ __launch_bounds__(256) void encode_seg(
    const float* __restrict__ x, const float* __restrict__ xm,
    const int* __restrict__ batch, const float* __restrict__ W,
    const float* __restrict__ b, float* __restrict__ h,
    float* __restrict__ gsum, float* __restrict__ gcnt,
    float* __restrict__ bcsum, float* __restrict__ bccnt) {
  __shared__ float xs5[128 * 5];
  __shared__ float xm3[128 * 3];
  __shared__ float ls[Bb * 128];
  __shared__ float lb[Bb * 128];
  __shared__ float lc[Bb], lbc[Bb];
  const int t = threadIdx.x;
  const int nBase = blockIdx.x * 128;
  const int j = t & 127, half = t >> 7;
  const int base5 = nBase * 5, base3 = nBase * 3;
  for (int q = t; q < 640; q += 256) xs5[q] = (base5 + q < Nn * 5) ? x[base5 + q] : 0.f;
  for (int q = t; q < 384; q += 256) xm3[q] = (base3 + q < Nn * 3) ? xm[base3 + q] : 0.f;
  for (int q = t; q < Bb * 128; q += 256) { ls[q] = 0.f; lb[q] = 0.f; }
  if (t < Bb) { lc[t] = 0.f; lbc[t] = 0.f; }
  float Wcol[8];
#pragma unroll
  for (int k = 0; k < 8; k++) Wcol[k] = W[k * 128 + j];
  const float bj = b[j];
  __syncthreads();
  int curb = -1;
  float runh = 0.f, runb = 0.f, runc = 0.f, runbc = 0.f;
  for (int kk = 0; kk < 64; kk++) {
    int i = nBase + kk * 2 + half;
    if (i >= Nn) break;
    int li = i - nBase;
    float acc = bj;
#pragma unroll
    for (int k = 0; k < 5; k++) acc = fmaf(xs5[li * 5 + k], Wcol[k], acc);
#pragma unroll
    for (int k = 0; k < 3; k++) acc = fmaf(xm3[li * 3 + k], Wcol[5 + k], acc);
    float v = fmaxf(acc, 0.f);
    h[(size_t)i * 128 + j] = v;
    float bc = xm3[li * 3 + 2];
    int g = batch[i];
    if (g != curb) {
      if (curb >= 0) {
        atomicAdd(&ls[curb * 128 + j], runh);
        atomicAdd(&lb[curb * 128 + j], runb);
        if (j == 0) { atomicAdd(&lc[curb], runc); atomicAdd(&lbc[curb], runbc); }
      }
      curb = g; runh = runb = runc = runbc = 0.f;
    }
    runh += v; runb += v * bc;
    if (j == 0) { runc += 1.f; runbc += bc; }
  }
  if (curb >= 0) {
    atomicAdd(&ls[curb * 128 + j], runh);
    atomicAdd(&lb[curb * 128 + j], runb);
    if (j == 0) { atomicAdd(&lc[curb], runc); atomicAdd(&lbc[curb], runbc); }
  }
  __syncthreads();
  for (int q = t; q < Bb * 128; q += 256) {
    float a = ls[q], c = lb[q];
    if (a != 0.f) atomicAdd(&gsum[q], a);
    if (c != 0.f) atomicAdd(&bcsum[q], c);
  }
  if (t < Bb) { atomicAdd(&gcnt[t], lc[t]); atomicAdd(&bccnt[t], lbc[t]); }
}

// ---------------------------------------------------------------- weight split (once per launch)
__global__ __launch_bounds__(256) void split_w_kernel(
    const float* __restrict__ Wm, const float* __restrict__ Wu,
    short* __restrict__ Wmt_h, short* __restrict__ Wmt_l,
    short* __restrict__ Wut_h, short* __restrict__ Wut_l) {
  int idx = blockIdx.x * 256 + threadIdx.x;
  if (idx < 32768) {
    int k = idx & 127, n = (idx >> 7) & 127, y = idx >> 14;
    float w = Wm[(size_t)(y * 128 + k) * 128 + n];
    short hi = f2bf(w);
    Wmt_h[idx] = hi;
    Wmt_l[idx] = f2bf(w - bf2f(hi));
  } else if (idx < 65536) {
    int j = idx - 32768;
    int k = j & 255, n = j >> 8;
    float w = Wu[(size_t)k * 128 + n];
    short hi = f2bf(w);
    Wut_h[j] = hi;
    Wut_l[j] = f2bf(w - bf2f(hi));
  }
}

// ---------------------------------------------------------------- CSR build
// cnt/scatter sliced by dst range: slice = blockIdx&7 -> one XCD per slice
// (round-robin heuristic), so the slice's cnt/cursor/rec lines stay in that
// XCD's L2 and write back once instead of bouncing across 8 L2s.
__global__ void cnt_kernel(const int* __restrict__ ei, int* __restrict__ cnt) {
  int slice = blockIdx.x & (NSL - 1);
  int bs = blockIdx.x >> 3;
  int lo = slice * SLN, hi = lo + SLN;
  for (int e = bs * 256 + threadIdx.x; e < Ee; e += SLB * 256) {
    int d = ei[Ee + e];
    if (d >= lo && d < hi) atomicAdd(&cnt[d], 1);
  }
}
__global__ __launch_bounds__(256) void bsum_kernel(const int* __restrict__ cnt,
                                                   int* __restrict__ bsum) {
  __shared__ int wsum[4];
  int t = threadIdx.x;
  int i = blockIdx.x * 256 + t;
  int v = (i < Nn) ? cnt[i] : 0;
#pragma unroll
  for (int off = 32; off > 0; off >>= 1) v += __shfl_down(v, off);
  if ((t & 63) == 0) wsum[t >> 6] = v;
  __syncthreads();
  if (t == 0) bsum[blockIdx.x] = wsum[0] + wsum[1] + wsum[2] + wsum[3];
}
__global__ __launch_bounds__(256) void scan_top_kernel(const int* __restrict__ bsum,
                                                       int* __restrict__ boff) {
  __shared__ int s[256];
  int t = threadIdx.x;
  int v = (t < SCB) ? bsum[t] : 0;
  s[t] = v;
  __syncthreads();
  for (int off = 1; off < 256; off <<= 1) {
    int x = (t >= off) ? s[t - off] : 0;
    __syncthreads();
    s[t] += x;
    __syncthreads();
  }
  boff[t] = s[t] - v;  // exclusive
}
__global__ __launch_bounds__(256) void apply_kernel(
    const int* __restrict__ cnt, const int* __restrict__ boff,
    int* __restrict__ cursor, int* __restrict__ rowptr,
    float* __restrict__ invdeg) {
  __shared__ int s[256];
  int t = threadIdx.x;
  int i = blockIdx.x * 256 + t;
  int v = (i < Nn) ? cnt[i] : 0;
  s[t] = v;
  __syncthreads();
  for (int off = 1; off < 256; off <<= 1) {
    int x = (t >= off) ? s[t - off] : 0;
    __syncthreads();
    s[t] += x;
    __syncthreads();
  }
  int ex = boff[blockIdx.x] + s[t] - v;
  if (i < Nn) {
    cursor[i] = ex;
    rowptr[i] = ex;
    invdeg[i] = 1.0f / fmaxf((float)v, 1.0f);
    if (i == Nn - 1) rowptr[Nn] = ex + v;
  }
}
// scatter: ONE packed 8B record {src:u16, ea0:bf16, ea1:bf16, ea2:bf16};
// dst-sliced for XCD-local L2 write-back.
__global__ void scatter_kernel(const int* __restrict__ ei, const float* __restrict__ ea,
                               int* __restrict__ cursor, int2* __restrict__ rec) {
  int slice = blockIdx.x & (NSL - 1);
  int bs = blockIdx.x >> 3;
  int lo = slice * SLN, hi = lo + SLN;
  for (int e = bs * 256 + threadIdx.x; e < Ee; e += SLB * 256) {
    int d = ei[Ee + e];
    if (d >= lo && d < hi) {
      int p = atomicAdd(&cursor[d], 1);
      unsigned r0 = (unsigned)ei[e] |
                    ((unsigned)(unsigned short)f2bf(ea[3 * (size_t)e + 0]) << 16);
      unsigned r1 = (unsigned)(unsigned short)f2bf(ea[3 * (size_t)e + 1]) |
                    ((unsigned)(unsigned short)f2bf(ea[3 * (size_t)e + 2]) << 16);
      rec[p] = make_int2((int)r0, (int)r1);
    }
  }
}

// gb_static[g] = xbc[g] @ Wu[384:512] + bu
__global__ __launch_bounds__(128) void gb_static_kernel(
    const float* __restrict__ bcsum, const float* __restrict__ bccnt,
    const float* __restrict__ Wu, const float* __restrict__ bu,
    float* __restrict__ gbst) {
  __shared__ float xb[128];
  int g = blockIdx.x, t = threadIdx.x;
  xb[t] = bcsum[g * 128 + t] / fmaxf(bccnt[g], 1.f);
  __syncthreads();
  float acc = bu[t];
#pragma unroll 4
  for (int k = 0; k < 128; k++) acc = fmaf(xb[k], Wu[(size_t)(384 + k) * 128 + t], acc);
  gbst[g * 128 + t] = acc;
}

// gb[g] = gb_static[g] + xg[g] @ Wu[256:384]
__global__ __launch_bounds__(128) void gb_dyn_kernel(
    const float* __restrict__ gsum, const float* __restrict__ gcnt,
    const float* __restrict__ gbst, const float* __restrict__ Wu,
    float* __restrict__ gb) {
  __shared__ float xg[128];
  int g = blockIdx.x, t = threadIdx.x;
  xg[t] = gsum[g * 128 + t] / fmaxf(gcnt[g], 1.f);
  __syncthreads();
  float acc = gbst[g * 128 + t];
#pragma unroll 4
  for (int k = 0; k < 128; k++) acc = fmaf(xg[k], Wu[(size_t)(256 + k) * 128 + t], acc);
  gb[g * 128 + t] = acc;
}

// ---------------------------------------------------------------- proj (MFMA split-bf16)
// blockIdx.y==0: hs8 (fp8 e4m3) = h @ Wm[0:128]
// blockIdx.y==1: hdbf (bf16)    = h @ Wm[128:256]
__global__ __launch_bounds__(256) void proj_mfma(
    const float* __restrict__ h, const short* __restrict__ Wth,
    const short* __restrict__ Wtl, unsigned char* __restrict__ hs8,
    unsigned short* __restrict__ hdbf) {
  __shared__ short Ah_s[128 * AP], Al_s[128 * AP];
  __shared__ short Bh_s[128 * AP], Bl_s[128 * AP];
  const int t = threadIdx.x;
  const int nBase = blockIdx.x * 128;
  const int yoff = blockIdx.y * 16384;
  const int wave = t >> 6, lane = t & 63;
  const int ml = lane & 15, quad = lane >> 4;
  const int ko = quad * 8;

  f32x4 acc[2][8];
#pragma unroll
  for (int nt = 0; nt < 2; nt++)
#pragma unroll
    for (int mt = 0; mt < 8; mt++)
#pragma unroll
      for (int q = 0; q < 4; q++) acc[nt][mt][q] = 0.f;

  const int srow = t >> 1;
  const int kc = (t & 1) * 16;
  const int nd0 = nBase + srow;
  const int nn = nd0 < Nn ? nd0 : Nn - 1;

  for (int c = 0; c < 4; c++) {
    const float* p = &h[(size_t)nn * 128 + c * 32 + kc];
    float4 u0 = *(const float4*)(p + 0);
    float4 u1 = *(const float4*)(p + 4);
    float4 u2 = *(const float4*)(p + 8);
    float4 u3 = *(const float4*)(p + 12);
    const int k0 = c * 32;
    const bf16x8 gb0 = *(const bf16x8*)&Wth[(size_t)yoff + srow * 128 + k0 + kc];
    const bf16x8 gb1 = *(const bf16x8*)&Wth[(size_t)yoff + srow * 128 + k0 + kc + 8];
    const bf16x8 gl0 = *(const bf16x8*)&Wtl[(size_t)yoff + srow * 128 + k0 + kc];
    const bf16x8 gl1 = *(const bf16x8*)&Wtl[(size_t)yoff + srow * 128 + k0 + kc + 8];
    float xs[16] = {u0.x,u0.y,u0.z,u0.w, u1.x,u1.y,u1.z,u1.w,
                    u2.x,u2.y,u2.z,u2.w, u3.x,u3.y,u3.z,u3.w};
    bf16x8 vh0, vh1, vl0, vl1;
#pragma unroll
    for (int j = 0; j < 8; j++) {
      short hi = f2bf(xs[j]);
      vh0[j] = hi; vl0[j] = f2bf(xs[j] - bf2f(hi));
    }
#pragma unroll
    for (int j = 0; j < 8; j++) {
      short hi = f2bf(xs[8 + j]);
      vh1[j] = hi; vl1[j] = f2bf(xs[8 + j] - bf2f(hi));
    }
    __syncthreads();
    *(bf16x8*)&Ah_s[srow * AP + kc] = vh0;
    *(bf16x8*)&Ah_s[srow * AP + kc + 8] = vh1;
    *(bf16x8*)&Al_s[srow * AP + kc] = vl0;
    *(bf16x8*)&Al_s[srow * AP + kc + 8] = vl1;
    *(bf16x8*)&Bh_s[srow * AP + kc] = gb0;
    *(bf16x8*)&Bh_s[srow * AP + kc + 8] = gb1;
    *(bf16x8*)&Bl_s[srow * AP + kc] = gl0;
    *(bf16x8*)&Bl_s[srow * AP + kc + 8] = gl1;
    __syncthreads();
#pragma unroll
    for (int mt = 0; mt < 8; mt++) {
      const int ar = (mt * 16 + ml) * AP + ko;
      bf16x8 ah = *(const bf16x8*)&Ah_s[ar];
      bf16x8 al = *(const bf16x8*)&Al_s[ar];
#pragma unroll
      for (int nt = 0; nt < 2; nt++) {
        const int br = (wave * 32 + nt * 16 + ml) * AP + ko;
        bf16x8 bh = *(const bf16x8*)&Bh_s[br];
        bf16x8 bl = *(const bf16x8*)&Bl_s[br];
        acc[nt][mt] = __builtin_amdgcn_mfma_f32_16x16x32_bf16(ah, bh, acc[nt][mt], 0, 0, 0);
        acc[nt][mt] = __builtin_amdgcn_mfma_f32_16x16x32_bf16(ah, bl, acc[nt][mt], 0, 0, 0);
        acc[nt][mt] = __builtin_amdgcn_mfma_f32_16x16x32_bf16(al, bh, acc[nt][mt], 0, 0, 0);
      }
    }
  }
  if (blockIdx.y == 0) {
#pragma unroll
    for (int nt = 0; nt < 2; nt++) {
      const int ch = wave * 32 + nt * 16 + ml;
#pragma unroll
      for (int mt = 0; mt < 8; mt++) {
#pragma unroll
        for (int q = 0; q < 4; q++) {
          int nd = nBase + mt * 16 + quad * 4 + q;
          if (nd < Nn) {
            int pk = __builtin_amdgcn_cvt_pk_fp8_f32(acc[nt][mt][q], acc[nt][mt][q], 0, false);
            hs8[(size_t)nd * 128 + ch] = (unsigned char)(pk & 0xff);
          }
        }
      }
    }
  } else {
#pragma unroll
    for (int nt = 0; nt < 2; nt++) {
      const int ch = wave * 32 + nt * 16 + ml;
#pragma unroll
      for (int mt = 0; mt < 8; mt++) {
#pragma unroll
        for (int q = 0; q < 4; q++) {
          int nd = nBase + mt * 16 + quad * 4 + q;
          if (nd < Nn) hdbf[(size_t)nd * 128 + ch] = (unsigned short)f2bf(acc[nt][mt][q]);
        }
      }
    }
  }
}

// ---------------------------------------------------------------- edge pass / aggregation
__global__ __launch_bounds__(256) void agg_kernel(
    const unsigned char* __restrict__ hs8, const unsigned short* __restrict__ hdbf,
    unsigned short* __restrict__ aggbf, const int2* __restrict__ rec,
    const int* __restrict__ rowptr, const float* __restrict__ invdeg,
    const float* __restrict__ Wm, const float* __restrict__ bm) {
  int t = threadIdx.x;
  int hw = t >> 5, lane = t & 31;
  int v = blockIdx.x * 8 + hw;
  if (v >= Nn) return;
  int c0 = lane * 4;
  const float4 We0 = *(const float4*)&Wm[(size_t)256 * 128 + c0];
  const float4 We1 = *(const float4*)&Wm[(size_t)257 * 128 + c0];
  const float4 We2 = *(const float4*)&Wm[(size_t)258 * 128 + c0];
  const float4 b4  = *(const float4*)&bm[c0];
  const ushort4 hd4 = *(const ushort4*)&hdbf[(size_t)v * 128 + c0];
  const float bx = b4.x + bf2f((short)hd4.x), by = b4.y + bf2f((short)hd4.y),
              bz = b4.z + bf2f((short)hd4.z), bw = b4.w + bf2f((short)hd4.w);
  float ax = 0.f, ay = 0.f, az = 0.f, aw = 0.f;
  float ax2 = 0.f, ay2 = 0.f, az2 = 0.f, aw2 = 0.f;
  const int r0 = rowptr[v], r1 = rowptr[v + 1];
  int e = r0;
  for (; e + 2 <= r1; e += 2) {
    int2 q0 = rec[e], q1 = rec[e + 1];
    int s0 = q0.x & 0xffff, s1 = q1.x & 0xffff;
    unsigned hr0 = *(const unsigned*)&hs8[(size_t)s0 * 128 + c0];
    unsigned hr1 = *(const unsigned*)&hs8[(size_t)s1 * 128 + c0];
    float e00 = bf2f((short)(q0.x >> 16));
    float e01 = bf2f((short)(q0.y & 0xffff));
    float e02 = bf2f((short)(q0.y >> 16));
    float e10 = bf2f((short)(q1.x >> 16));
    float e11 = bf2f((short)(q1.y & 0xffff));
    float e12 = bf2f((short)(q1.y >> 16));
    float h0x = __builtin_amdgcn_cvt_f32_fp8(hr0, 0);
    float h0y = __builtin_amdgcn_cvt_f32_fp8(hr0, 1);
    float h0z = __builtin_amdgcn_cvt_f32_fp8(hr0, 2);
    float h0w = __builtin_amdgcn_cvt_f32_fp8(hr0, 3);
    float h1x = __builtin_amdgcn_cvt_f32_fp8(hr1, 0);
    float h1y = __builtin_amdgcn_cvt_f32_fp8(hr1, 1);
    float h1z = __builtin_amdgcn_cvt_f32_fp8(hr1, 2);
    float h1w = __builtin_amdgcn_cvt_f32_fp8(hr1, 3);
    ax += fmaxf(fmaf(e00, We0.x, fmaf(e01, We1.x, fmaf(e02, We2.x, h0x + bx))), 0.f);
    ay += fmaxf(fmaf(e00, We0.y, fmaf(e01, We1.y, fmaf(e02, We2.y, h0y + by))), 0.f);
    az += fmaxf(fmaf(e00, We0.z, fmaf(e01, We1.z, fmaf(e02, We2.z, h0z + bz))), 0.f);
    aw += fmaxf(fmaf(e00, We0.w, fmaf(e01, We1.w, fmaf(e02, We2.w, h0w + bw))), 0.f);
    ax2 += fmaxf(fmaf(e10, We0.x, fmaf(e11, We1.x, fmaf(e12, We2.x, h1x + bx))), 0.f);
    ay2 += fmaxf(fmaf(e10, We0.y, fmaf(e11, We1.y, fmaf(e12, We2.y, h1y + by))), 0.f);
    az2 += fmaxf(fmaf(e10, We0.z, fmaf(e11, We1.z, fmaf(e12, We2.z, h1z + bz))), 0.f);
    aw2 += fmaxf(fmaf(e10, We0.w, fmaf(e11, We1.w, fmaf(e12, We2.w, h1w + bw))), 0.f);
  }
  if (e < r1) {
    int2 q0 = rec[e];
    int s0 = q0.x & 0xffff;
    unsigned hr0 = *(const unsigned*)&hs8[(size_t)s0 * 128 + c0];
    float e00 = bf2f((short)(q0.x >> 16));
    float e01 = bf2f((short)(q0.y & 0xffff));
    float e02 = bf2f((short)(q0.y >> 16));
    float h0x = __builtin_amdgcn_cvt_f32_fp8(hr0, 0);
    float h0y = __builtin_amdgcn_cvt_f32_fp8(hr0, 1);
    float h0z = __builtin_amdgcn_cvt_f32_fp8(hr0, 2);
    float h0w = __builtin_amdgcn_cvt_f32_fp8(hr0, 3);
    ax += fmaxf(fmaf(e00, We0.x, fmaf(e01, We1.x, fmaf(e02, We2.x, h0x + bx))), 0.f);
    ay += fmaxf(fmaf(e00, We0.y, fmaf(e01, We1.y, fmaf(e02, We2.y, h0y + by))), 0.f);
    az += fmaxf(fmaf(e00, We0.z, fmaf(e01, We1.z, fmaf(e02, We2.z, h0z + bz))), 0.f);
    aw += fmaxf(fmaf(e00, We0.w, fmaf(e01, We1.w, fmaf(e02, We2.w, h0w + bw))), 0.f);
  }
  const float idg = invdeg[v];
  ushort4 o;
  o.x = (unsigned short)f2bf((ax + ax2) * idg);
  o.y = (unsigned short)f2bf((ay + ay2) * idg);
  o.z = (unsigned short)f2bf((az + az2) * idg);
  o.w = (unsigned short)f2bf((aw + aw2) * idg);
  *(ushort4*)&aggbf[(size_t)v * 128 + c0] = o;
}

// ---------------------------------------------------------------- update (MFMA split-bf16) + fused group-sum
__global__ __launch_bounds__(256) void updg_mfma(
    float* __restrict__ h, const unsigned short* __restrict__ aggbf,
    const int* __restrict__ batch,
    const short* __restrict__ Wth, const short* __restrict__ Wtl,
    const float* __restrict__ gb, float* __restrict__ gsum_out) {
  __shared__ short Ah_s[128 * AP], Al_s[128 * AP];
  __shared__ short Bh_s[128 * AP], Bl_s[128 * AP];
  __shared__ float gbs[Bb * 128];
  __shared__ float ls[Bb * 128];
  const int t = threadIdx.x;
  const int nBase = blockIdx.x * 128;
  *(float4*)&gbs[t * 4] = *(const float4*)&gb[t * 4];
#pragma unroll
  for (int q = 0; q < 4; q++) ls[t + q * 256] = 0.f;

  const int wave = t >> 6, lane = t & 63;
  const int ml = lane & 15, quad = lane >> 4;
  const int ko = quad * 8;

  f32x4 acc[2][8];
#pragma unroll
  for (int nt = 0; nt < 2; nt++)
#pragma unroll
    for (int mt = 0; mt < 8; mt++)
#pragma unroll
      for (int q = 0; q < 4; q++) acc[nt][mt][q] = 0.f;

  const int srow = t >> 1;
  const int kc = (t & 1) * 16;
  const int nd0 = nBase + srow;
  const int nn = nd0 < Nn ? nd0 : Nn - 1;

  for (int c = 0; c < 8; c++) {
    const int k0 = c * 32;
    bf16x8 vh0, vh1, vl0, vl1;
    if (c < 4) {
      const float* p = &h[(size_t)nn * 128 + c * 32 + kc];
      float4 u0 = *(const float4*)(p + 0);
      float4 u1 = *(const float4*)(p + 4);
      float4 u2 = *(const float4*)(p + 8);
      float4 u3 = *(const float4*)(p + 12);
      float xs[16] = {u0.x,u0.y,u0.z,u0.w, u1.x,u1.y,u1.z,u1.w,
                      u2.x,u2.y,u2.z,u2.w, u3.x,u3.y,u3.z,u3.w};
#pragma unroll
      for (int j = 0; j < 8; j++) {
        short hi = f2bf(xs[j]);
        vh0[j] = hi; vl0[j] = f2bf(xs[j] - bf2f(hi));
      }
#pragma unroll
      for (int j = 0; j < 8; j++) {
        short hi = f2bf(xs[8 + j]);
        vh1[j] = hi; vl1[j] = f2bf(xs[8 + j] - bf2f(hi));
      }
    } else {
      const unsigned short* pa = &aggbf[(size_t)nn * 128 + (c - 4) * 32 + kc];
      vh0 = *(const bf16x8*)(pa);
      vh1 = *(const bf16x8*)(pa + 8);
    }
    const bf16x8 gb0 = *(const bf16x8*)&Wth[(size_t)srow * 256 + k0 + kc];
    const bf16x8 gb1 = *(const bf16x8*)&Wth[(size_t)srow * 256 + k0 + kc + 8];
    const bf16x8 gl0 = *(const bf16x8*)&Wtl[(size_t)srow * 256 + k0 + kc];
    const bf16x8 gl1 = *(const bf16x8*)&Wtl[(size_t)srow * 256 + k0 + kc + 8];
    __syncthreads();
    *(bf16x8*)&Ah_s[srow * AP + kc] = vh0;
    *(bf16x8*)&Ah_s[srow * AP + kc + 8] = vh1;
    if (c < 4) {
      *(bf16x8*)&Al_s[srow * AP + kc] = vl0;
      *(bf16x8*)&Al_s[srow * AP + kc + 8] = vl1;
    }
    *(bf16x8*)&Bh_s[srow * AP + kc] = gb0;
    *(bf16x8*)&Bh_s[srow * AP + kc + 8] = gb1;
    *(bf16x8*)&Bl_s[srow * AP + kc] = gl0;
    *(bf16x8*)&Bl_s[srow * AP + kc + 8] = gl1;
    __syncthreads();
    if (c < 4) {
#pragma unroll
      for (int mt = 0; mt < 8; mt++) {
        const int ar = (mt * 16 + ml) * AP + ko;
        bf16x8 ah = *(const bf16x8*)&Ah_s[ar];
        bf16x8 al = *(const bf16x8*)&Al_s[ar];
#pragma unroll
        for (int nt = 0; nt < 2; nt++) {
          const int br = (wave * 32 + nt * 16 + ml) * AP + ko;
          bf16x8 bh = *(const bf16x8*)&Bh_s[br];
          bf16x8 bl = *(const bf16x8*)&Bl_s[br];
          acc[nt][mt] = __builtin_amdgcn_mfma_f32_16x16x32_bf16(ah, bh, acc[nt][mt], 0, 0, 0);
          acc[nt][mt] = __builtin_amdgcn_mfma_f32_16x16x32_bf16(ah, bl, acc[nt][mt], 0, 0, 0);
          acc[nt][mt] = __builtin_amdgcn_mfma_f32_16x16x32_bf16(al, bh, acc[nt][mt], 0, 0, 0);
        }
      }
    } else {
#pragma unroll
      for (int mt = 0; mt < 8; mt++) {
        const int ar = (mt * 16 + ml) * AP + ko;
        bf16x8 ah = *(const bf16x8*)&Ah_s[ar];
#pragma unroll
        for (int nt = 0; nt < 2; nt++) {
          const int br = (wave * 32 + nt * 16 + ml) * AP + ko;
          bf16x8 bh = *(const bf16x8*)&Bh_s[br];
          bf16x8 bl = *(const bf16x8*)&Bl_s[br];
          acc[nt][mt] = __builtin_amdgcn_mfma_f32_16x16x32_bf16(ah, bh, acc[nt][mt], 0, 0, 0);
          acc[nt][mt] = __builtin_amdgcn_mfma_f32_16x16x32_bf16(ah, bl, acc[nt][mt], 0, 0, 0);
        }
      }
    }
  }
#pragma unroll
  for (int nt = 0; nt < 2; nt++) {
    const int ch = wave * 32 + nt * 16 + ml;
#pragma unroll
    for (int mt = 0; mt < 8; mt++) {
      int rbase = nBase + mt * 16 + quad * 4;
      float runv = 0.f;
      int curb = -1;
#pragma unroll
      for (int q = 0; q < 4; q++) {
        int nd = rbase + q;
        if (nd < Nn) {
          int bi = batch[nd];
          float u = fmaxf(acc[nt][mt][q] + gbs[bi * 128 + ch], 0.f);
          float hn = h[(size_t)nd * 128 + ch] + u;
          h[(size_t)nd * 128 + ch] = hn;
          if (bi != curb) {
            if (curb >= 0) atomicAdd(&ls[curb * 128 + ch], runv);
            curb = bi;
            runv = 0.f;
          }
          runv += hn;
        }
      }
      if (curb >= 0) atomicAdd(&ls[curb * 128 + ch], runv);
    }
  }
  __syncthreads();
#pragma unroll
  for (int q = 0; q < 4; q++) {
    int idx = t + q * 256;
    float v = ls[idx];
    if (v != 0.f) atomicAdd(&gsum_out[idx], v);
  }
}

// ---------------------------------------------------------------- kwv (MFMA bf16) + fused decode
__global__ __launch_bounds__(256) void kwv_kernel(
    const float* __restrict__ h, const float* __restrict__ pos,
    const float* __restrict__ Fm, const float* __restrict__ Wd,
    const float* __restrict__ bd, float* __restrict__ partial,
    float* __restrict__ ksum, float* __restrict__ out) {
  __shared__ float h_s[32 * HP];     // fp32 tile for decode
  __shared__ short nkT[128 * KS];    // A: nkT[m][k]
  __shared__ short hT[128 * KS];     // B: hT[n][k]
  __shared__ float wd[512];
  __shared__ float ksum_s[128];
  const int t = threadIdx.x;
  const int hr = t >> 3;
  const int hc = (t & 7) * 16;
  const int fg = (t & 7) * 8;
  const int wave = t >> 6, lane = t & 63;
  const int ml = lane & 15, quad = lane >> 4;
  const int ko = quad * 8;
  if (t < 128) { *(float4*)&wd[t * 4] = *(const float4*)&Wd[t * 4]; ksum_s[t] = 0.f; }
  const float bdv = bd[t & 3];
  f32x4 acc[2][8];
#pragma unroll
  for (int nt = 0; nt < 2; nt++)
#pragma unroll
    for (int mt = 0; mt < 8; mt++)
#pragma unroll
      for (int q = 0; q < 4; q++) acc[nt][mt][q] = 0.f;
  float klc[8], kls[8];
#pragma unroll
  for (int f = 0; f < 8; f++) { klc[f] = 0.f; kls[f] = 0.f; }

  const int nTiles = (Nn + 31) / 32;  // 1563
  for (int tile = blockIdx.x; tile < nTiles; tile += gridDim.x) {
    const int gh = tile * 32 + hr;
    float4 hv0 = {0.f, 0.f, 0.f, 0.f}, hv1 = hv0, hv2 = hv0, hv3 = hv0;
    float cbuf[8], sbuf[8];
    if (gh < Nn) {
      const float* hp = &h[(size_t)gh * 128 + hc];
      hv0 = *(const float4*)(hp + 0);
      hv1 = *(const float4*)(hp + 4);
      hv2 = *(const float4*)(hp + 8);
      hv3 = *(const float4*)(hp + 12);
      const float px = pos[gh * 2 + 0], py = pos[gh * 2 + 1];
#pragma unroll
      for (int f = 0; f < 8; f++) {
        float p = px * Fm[fg + f] + py * Fm[64 + fg + f];
        cbuf[f] = cosf(p) * 0.125f;
        sbuf[f] = sinf(p) * 0.125f;
      }
    } else {
#pragma unroll
      for (int f = 0; f < 8; f++) { cbuf[f] = 0.f; sbuf[f] = 0.f; }
    }
    float xs[16] = {hv0.x,hv0.y,hv0.z,hv0.w, hv1.x,hv1.y,hv1.z,hv1.w,
                    hv2.x,hv2.y,hv2.z,hv2.w, hv3.x,hv3.y,hv3.z,hv3.w};
    __syncthreads();
    *(float4*)&h_s[hr * HP + hc + 0]  = hv0;
    *(float4*)&h_s[hr * HP + hc + 4]  = hv1;
    *(float4*)&h_s[hr * HP + hc + 8]  = hv2;
    *(float4*)&h_s[hr * HP + hc + 12] = hv3;
#pragma unroll
    for (int i = 0; i < 16; i++) hT[(hc + i) * KS + hr] = f2bf(xs[i]);
#pragma unroll
    for (int f = 0; f < 8; f++) {
      nkT[(fg + f) * KS + hr] = f2bf(cbuf[f]);
      nkT[(64 + fg + f) * KS + hr] = f2bf(sbuf[f]);
      klc[f] += cbuf[f];
      kls[f] += sbuf[f];
    }
    __syncthreads();
#pragma unroll
    for (int mt = 0; mt < 8; mt++) {
      bf16x8 ah = *(const bf16x8*)&nkT[(mt * 16 + ml) * KS + ko];
#pragma unroll
      for (int nt = 0; nt < 2; nt++) {
        bf16x8 bh = *(const bf16x8*)&hT[(wave * 32 + nt * 16 + ml) * KS + ko];
        acc[nt][mt] = __builtin_amdgcn_mfma_f32_16x16x32_bf16(ah, bh, acc[nt][mt], 0, 0, 0);
      }
    }
    if (t < 128) {  // fused decode (fp32)
      int n = t >> 2, o = t & 3;
      int gn = tile * 32 + n;
      if (gn < Nn) {
        float s = bdv;
#pragma unroll 4
        for (int kk = 0; kk < 128; kk++) {
          int k = (kk + n) & 127;
          s = fmaf(h_s[n * HP + k], wd[k * 4 + o], s);
        }
        out[4 + (size_t)gn * 4 + o] = s;
      }
    }
  }
  float* pb = &partial[(size_t)blockIdx.x * 16384];
#pragma unroll
  for (int nt = 0; nt < 2; nt++) {
    const int col = wave * 32 + nt * 16 + ml;
#pragma unroll
    for (int mt = 0; mt < 8; mt++) {
#pragma unroll
      for (int q = 0; q < 4; q++) {
        int row = mt * 16 + quad * 4 + q;
        pb[row * 128 + col] = acc[nt][mt][q];
      }
    }
  }
#pragma unroll
  for (int f = 0; f < 8; f++) {
    atomicAdd(&ksum_s[fg + f], klc[f]);
    atomicAdd(&ksum_s[64 + fg + f], kls[f]);
  }
  __syncthreads();
  if (t < 128) atomicAdd(&ksum[t], ksum_s[t]);
}

__global__ __launch_bounds__(256) void kwv_reduce(const float* __restrict__ partial,
                                                  float* __restrict__ kwv) {
  int idx = blockIdx.x * 256 + threadIdx.x;
  float s = 0.f;
  for (int b = 0; b < KWVB; b++) s += partial[(size_t)b * 16384 + idx];
  kwv[idx] = s;
}

// ---------------------------------------------------------------- final sampling head
__global__ __launch_bounds__(128) void final_kernel(
    const float* __restrict__ sp, const float* __restrict__ Fm,
    const float* __restrict__ kwv, const float* __restrict__ vs,
    const float* __restrict__ ksum, const float* __restrict__ Wd,
    const float* __restrict__ bd, float* __restrict__ out) {
  __shared__ float nq_s[128];
  __shared__ float red[2];
  __shared__ float redU[8];
  int t = threadIdx.x;
  int jj = t & 63;
  float p = sp[0] * Fm[jj] + sp[1] * Fm[64 + jj];
  nq_s[t] = ((t < 64) ? cosf(p) : sinf(p)) * 0.125f;  // ||q||=sqrt(0.5) exact
  __syncthreads();
  float num = 0.f;
#pragma unroll
  for (int g = 0; g < Bb; g++) num += vs[g * 128 + t];
  for (int k = 0; k < 128; k++) num = fmaf(nq_s[k], kwv[k * 128 + t], num);
  float dp = nq_s[t] * ksum[t];
#pragma unroll
  for (int off = 32; off > 0; off >>= 1) dp += __shfl_down(dp, off);
  if ((t & 63) == 0) red[t >> 6] = dp;
  __syncthreads();
  float den = (float)Nn + red[0] + red[1];
  float e = num / den;
  float u[4];
#pragma unroll
  for (int o = 0; o < 4; o++) u[o] = e * Wd[t * 4 + o];
#pragma unroll
  for (int off = 32; off > 0; off >>= 1) {
#pragma unroll
    for (int o = 0; o < 4; o++) u[o] += __shfl_down(u[o], off);
  }
  if ((t & 63) == 0) {
#pragma unroll
    for (int o = 0; o < 4; o++) redU[(t >> 6) * 4 + o] = u[o];
  }
  __syncthreads();
  if (t < 4) out[t] = redU[t] + redU[4 + t] + bd[t];
}

// ---------------------------------------------------------------- launcher
extern "C" void kernel_launch(void* const* d_in, const int* in_sizes, int n_in,
                              void* d_out, int out_size, void* d_ws, size_t ws_size,
                              hipStream_t stream) {
  const float* x    = (const float*)d_in[0];
  const float* xm   = (const float*)d_in[1];
  const int*   ei   = (const int*)d_in[2];
  const float* ea   = (const float*)d_in[3];
  const float* pos  = (const float*)d_in[4];
  const int*   batch= (const int*)d_in[5];
  const float* sp   = (const float*)d_in[6];
  const float* Fm   = (const float*)d_in[7];
  const float* Wenc = (const float*)d_in[8];
  const float* benc = (const float*)d_in[9];
  const float* Wmsg = (const float*)d_in[10];
  const float* bmsg = (const float*)d_in[11];
  const float* Wupd = (const float*)d_in[12];
  const float* bupd = (const float*)d_in[13];
  const float* Wdec = (const float*)d_in[14];
  const float* bdec = (const float*)d_in[15];
  float* out = (float*)d_out;

  float* ws     = (float*)d_ws;
  float* h      = ws;                              // N*128
  float* agg    = h + (size_t)Nn * 128;            // region: aggbf (12.8MB); kwv partials span
  float* aux    = agg + (size_t)Nn * 128;          // region: hs8 (6.4MB) + hdbf (12.8MB)
  float* invdeg = aux + (size_t)Nn * 128;          // N
  // ---- zeroed region (6416 floats) ----
  float* gsum   = invdeg + Nn;                     // 1024
  float* gcnt   = gsum + 1024;                     // 8
  float* bcsum  = gcnt + 8;                        // 1024
  float* bccnt  = bcsum + 1024;                    // 8
  float* gsumR  = bccnt + 8;                       // 4*1024
  float* vsum   = gsumR + 4096;                    // 128 (unused)
  float* ksum   = vsum + 128;                      // 128
  // ---- end zeroed region ----
  float* gbst   = ksum + 128;                      // 1024
  float* gbuf   = gbst + 1024;                     // 4*1024
  float* kwv    = gbuf + 4096;                     // 16384
  int2*  rec    = (int2*)(kwv + 16384);            // E (packed 8B)
  int*   cnt    = (int*)(rec + Ee);                // N
  int*   cursor = cnt + Nn;                        // N
  int*   rowptr = cursor + Nn;                     // N+1
  int*   bsum   = rowptr + Nn + 1;                 // 256
  int*   boff   = bsum + 256;                      // 256
  short* wmt_h  = (short*)(boff + 256);            // 2*128*128
  short* wmt_l  = wmt_h + 32768;
  short* wut_h  = wmt_l + 32768;                   // 128*256
  short* wut_l  = wut_h + 32768;

  unsigned short* aggbf = (unsigned short*)agg;                     // 12.8 MB
  unsigned char*  hs8   = (unsigned char*)aux;                      // 6.4 MB
  unsigned short* hdbf  = (unsigned short*)(hs8 + (size_t)Nn * 128);// 12.8 MB

  hipMemsetAsync(gsum, 0, 6416 * sizeof(float), stream);
  hipMemsetAsync(cnt, 0, Nn * sizeof(int), stream);

  split_w_kernel<<<256, 256, 0, stream>>>(Wmsg, Wupd, wmt_h, wmt_l, wut_h, wut_l);

  // CSR build (dst-sorted packed records) — sliced by dst range for XCD-local L2
  cnt_kernel<<<NSL * SLB, 256, 0, stream>>>(ei, cnt);
  bsum_kernel<<<SCB, 256, 0, stream>>>(cnt, bsum);
  scan_top_kernel<<<1, 256, 0, stream>>>(bsum, boff);
  apply_kernel<<<SCB, 256, 0, stream>>>(cnt, boff, cursor, rowptr, invdeg);
  scatter_kernel<<<NSL * SLB, 256, 0, stream>>>(ei, ea, cursor, rec);

  const int nb128 = (Nn + 127) / 128;  // 391
  encode_seg<<<nb128, 256, 0, stream>>>(x, xm, batch, Wenc, benc, h,
                                        gsum, gcnt, bcsum, bccnt);
  gb_static_kernel<<<Bb, 128, 0, stream>>>(bcsum, bccnt, Wupd, bupd, gbst);
  gb_dyn_kernel<<<Bb, 128, 0, stream>>>(gsum, gcnt, gbst, Wupd, gbuf);

  for (int r = 0; r < ROUNDS; r++) {
    proj_mfma<<<dim3(nb128, 2), 256, 0, stream>>>(h, wmt_h, wmt_l, hs8, hdbf);
    agg_kernel<<<(Nn + 7) / 8, 256, 0, stream>>>(hs8, hdbf, aggbf, rec, rowptr,
                                                 invdeg, Wmsg, bmsg);
    updg_mfma<<<nb128, 256, 0, stream>>>(h, aggbf, batch, wut_h, wut_l,
                                         gbuf + r * 1024, gsumR + r * 1024);
    if (r < ROUNDS - 1)
      gb_dyn_kernel<<<Bb, 128, 0, stream>>>(gsumR + r * 1024, gcnt, gbst, Wupd,
                                            gbuf + (r + 1) * 1024);
  }

  // kwv partials alias the (now free) agg+aux regions: 512*64KB = 33.5 MB < 51.2 MB
  kwv_kernel<<<KWVB, 256, 0, stream>>>(h, pos, Fm, Wdec, bdec, agg, ksum, out);
  kwv_reduce<<<64, 256, 0, stream>>>(agg, kwv);
  final_kernel<<<1, 128, 0, stream>>>(sp, Fm, kwv, gsumR + 3 * 1024, ksum,
                                      Wdec, bdec, out);
}

// Round 15
// 708.790 us; speedup vs baseline: 1.0722x; 1.0722x over previous
//
#include <hip/hip_runtime.h>
#include <math.h>

#define Nn 50000
#define Ee 800000
#define Bb 8
#define ROUNDS 4
#define KWVB 512            // kwv partial blocks (2/CU)
#define SCB 196             // scan blocks (196*256 = 50176 >= Nn)
#define AP 40               // MFMA LDS row stride in shorts (32 k + 8 pad)
#define HP 132              // kwv fp32 h_s row stride (128 + 4 pad)
#define KS 40               // kwv bf16 transposed row stride in shorts
#define NBK 196             // dst buckets (dst >> 8)
#define P1B 391             // partition blocks
#define CHUNK 2047          // edges per partition block (391*2047 >= Ee)

typedef __attribute__((ext_vector_type(8))) short bf16x8;
typedef __attribute__((ext_vector_type(4))) float f32x4;

__device__ inline short f2bf(float f) {
  union { float f; unsigned u; } v; v.f = f;
  unsigned r = v.u + 0x7fff + ((v.u >> 16) & 1);  // RNE
  return (short)(r >> 16);
}
__device__ inline float bf2f(short s) {
  union { float f; unsigned u; } v; v.u = ((unsigned)(unsigned short)s) << 16;
  return v.f;
}

// ---------------------------------------------------------------- encode + fused segmean
__global__ __launch_bounds__(256) void encode_seg(
    const float* __restrict__ x, const float* __restrict__ xm,
    const int* __restrict__ batch, const float* __restrict__ W,
    const float* __restrict__ b, float* __restrict__ h,
    float* __restrict__ gsum, float* __restrict__ gcnt,
    float* __restrict__ bcsum, float* __restrict__ bccnt) {
  __shared__ float xs5[128 * 5];
  __shared__ float xm3[128 * 3];
  __shared__ float ls[Bb * 128];
  __shared__ float lb[Bb * 128];
  __shared__ float lc[Bb], lbc[Bb];
  const int t = threadIdx.x;
  const int nBase = blockIdx.x * 128;
  const int j = t & 127, half = t >> 7;
  const int base5 = nBase * 5, base3 = nBase * 3;
  for (int q = t; q < 640; q += 256) xs5[q] = (base5 + q < Nn * 5) ? x[base5 + q] : 0.f;
  for (int q = t; q < 384; q += 256) xm3[q] = (base3 + q < Nn * 3) ? xm[base3 + q] : 0.f;
  for (int q = t; q < Bb * 128; q += 256) { ls[q] = 0.f; lb[q] = 0.f; }
  if (t < Bb) { lc[t] = 0.f; lbc[t] = 0.f; }
  float Wcol[8];
#pragma unroll
  for (int k = 0; k < 8; k++) Wcol[k] = W[k * 128 + j];
  const float bj = b[j];
  __syncthreads();
  int curb = -1;
  float runh = 0.f, runb = 0.f, runc = 0.f, runbc = 0.f;
  for (int kk = 0; kk < 64; kk++) {
    int i = nBase + kk * 2 + half;
    if (i >= Nn) break;
    int li = i - nBase;
    float acc = bj;
#pragma unroll
    for (int k = 0; k < 5; k++) acc = fmaf(xs5[li * 5 + k], Wcol[k], acc);
#pragma unroll
    for (int k = 0; k < 3; k++) acc = fmaf(xm3[li * 3 + k], Wcol[5 + k], acc);
    float v = fmaxf(acc, 0.f);
    h[(size_t)i * 128 + j] = v;
    float bc = xm3[li * 3 + 2];
    int g = batch[i];
    if (g != curb) {
      if (curb >= 0) {
        atomicAdd(&ls[curb * 128 + j], runh);
        atomicAdd(&lb[curb * 128 + j], runb);
        if (j == 0) { atomicAdd(&lc[curb], runc); atomicAdd(&lbc[curb], runbc); }
      }
      curb = g; runh = runb = runc = runbc = 0.f;
    }
    runh += v; runb += v * bc;
    if (j == 0) { runc += 1.f; runbc += bc; }
  }
  if (curb >= 0) {
    atomicAdd(&ls[curb * 128 + j], runh);
    atomicAdd(&lb[curb * 128 + j], runb);
    if (j == 0) { atomicAdd(&lc[curb], runc); atomicAdd(&lbc[curb], runbc); }
  }
  __syncthreads();
  for (int q = t; q < Bb * 128; q += 256) {
    float a = ls[q], c = lb[q];
    if (a != 0.f) atomicAdd(&gsum[q], a);
    if (c != 0.f) atomicAdd(&bcsum[q], c);
  }
  if (t < Bb) { atomicAdd(&gcnt[t], lc[t]); atomicAdd(&bccnt[t], lbc[t]); }
}

// ---------------------------------------------------------------- weight split (once per launch)
__global__ __launch_bounds__(256) void split_w_kernel(
    const float* __restrict__ Wm, const float* __restrict__ Wu,
    short* __restrict__ Wmt_h, short* __restrict__ Wmt_l,
    short* __restrict__ Wut_h, short* __restrict__ Wut_l) {
  int idx = blockIdx.x * 256 + threadIdx.x;
  if (idx < 32768) {
    int k = idx & 127, n = (idx >> 7) & 127, y = idx >> 14;
    float w = Wm[(size_t)(y * 128 + k) * 128 + n];
    short hi = f2bf(w);
    Wmt_h[idx] = hi;
    Wmt_l[idx] = f2bf(w - bf2f(hi));
  } else if (idx < 65536) {
    int j = idx - 32768;
    int k = j & 255, n = j >> 8;
    float w = Wu[(size_t)k * 128 + n];
    short hi = f2bf(w);
    Wut_h[j] = hi;
    Wut_l[j] = f2bf(w - bf2f(hi));
  }
}

// ---------------------------------------------------------------- CSR build (radix partition)
// p0: per-block LDS bucket histogram -> 196 global atomics/block
__global__ __launch_bounds__(256) void bkt_cnt(const int* __restrict__ ei,
                                               int* __restrict__ bktcnt) {
  __shared__ int hist[NBK];
  int t = threadIdx.x;
  for (int q = t; q < NBK; q += 256) hist[q] = 0;
  __syncthreads();
  int base = blockIdx.x * CHUNK;
  int end = base + CHUNK < Ee ? base + CHUNK : Ee;
  for (int e = base + t; e < end; e += 256) atomicAdd(&hist[ei[Ee + e] >> 8], 1);
  __syncthreads();
  for (int q = t; q < NBK; q += 256)
    if (hist[q]) atomicAdd(&bktcnt[q], hist[q]);
}
// p0b: exclusive scan of 196 bucket counts -> bktbase[197], init bktcur
__global__ __launch_bounds__(256) void bkt_scan(const int* __restrict__ bktcnt,
                                                int* __restrict__ bktbase,
                                                int* __restrict__ bktcur) {
  __shared__ int s[256];
  int t = threadIdx.x;
  int v = (t < NBK) ? bktcnt[t] : 0;
  s[t] = v;
  __syncthreads();
  for (int off = 1; off < 256; off <<= 1) {
    int x = (t >= off) ? s[t - off] : 0;
    __syncthreads();
    s[t] += x;
    __syncthreads();
  }
  int ex = s[t] - v;
  if (t < NBK) { bktbase[t] = ex; bktcur[t] = ex; }
  if (t == NBK - 1) bktbase[NBK] = ex + v;
}
// p1: partition edges into bucket-contiguous staging (recA 8B + dlo 1B).
// Each block reserves per-bucket ranges -> writes are block-sequential per bucket.
__global__ __launch_bounds__(256) void bkt_part(
    const int* __restrict__ ei, const float* __restrict__ ea,
    int* __restrict__ bktcur, int2* __restrict__ recA,
    unsigned char* __restrict__ dlo) {
  __shared__ int hist[NBK], lbase[NBK], lcur[NBK];
  int t = threadIdx.x;
  for (int q = t; q < NBK; q += 256) hist[q] = 0;
  __syncthreads();
  int base = blockIdx.x * CHUNK;
  int end = base + CHUNK < Ee ? base + CHUNK : Ee;
  for (int e = base + t; e < end; e += 256) atomicAdd(&hist[ei[Ee + e] >> 8], 1);
  __syncthreads();
  for (int q = t; q < NBK; q += 256) {
    int c = hist[q];
    lbase[q] = c ? atomicAdd(&bktcur[q], c) : 0;
    lcur[q] = 0;
  }
  __syncthreads();
  for (int e = base + t; e < end; e += 256) {
    int d = ei[Ee + e];
    int bk = d >> 8;
    int p = lbase[bk] + atomicAdd(&lcur[bk], 1);
    unsigned r0 = (unsigned)ei[e] |
                  ((unsigned)(unsigned short)f2bf(ea[3 * (size_t)e + 0]) << 16);
    unsigned r1 = (unsigned)(unsigned short)f2bf(ea[3 * (size_t)e + 1]) |
                  ((unsigned)(unsigned short)f2bf(ea[3 * (size_t)e + 2]) << 16);
    recA[p] = make_int2((int)r0, (int)r1);
    dlo[p] = (unsigned char)(d & 255);
  }
}
// p2a: per-bucket dst histogram -> cnt (coalesced stores; replaces random atomics)
__global__ __launch_bounds__(256) void dst_cnt(const int* __restrict__ bktbase,
                                               const unsigned char* __restrict__ dlo,
                                               int* __restrict__ cnt) {
  __shared__ int hh[256];
  int t = threadIdx.x;
  hh[t] = 0;
  __syncthreads();
  int b = blockIdx.x;
  int lo = bktbase[b], hi = bktbase[b + 1];
  for (int i = lo + t; i < hi; i += 256) atomicAdd(&hh[dlo[i]], 1);
  __syncthreads();
  int d = b * 256 + t;
  if (d < Nn) cnt[d] = hh[t];
}
__global__ __launch_bounds__(256) void bsum_kernel(const int* __restrict__ cnt,
                                                   int* __restrict__ bsum) {
  __shared__ int wsum[4];
  int t = threadIdx.x;
  int i = blockIdx.x * 256 + t;
  int v = (i < Nn) ? cnt[i] : 0;
#pragma unroll
  for (int off = 32; off > 0; off >>= 1) v += __shfl_down(v, off);
  if ((t & 63) == 0) wsum[t >> 6] = v;
  __syncthreads();
  if (t == 0) bsum[blockIdx.x] = wsum[0] + wsum[1] + wsum[2] + wsum[3];
}
__global__ __launch_bounds__(256) void scan_top_kernel(const int* __restrict__ bsum,
                                                       int* __restrict__ boff) {
  __shared__ int s[256];
  int t = threadIdx.x;
  int v = (t < SCB) ? bsum[t] : 0;
  s[t] = v;
  __syncthreads();
  for (int off = 1; off < 256; off <<= 1) {
    int x = (t >= off) ? s[t - off] : 0;
    __syncthreads();
    s[t] += x;
    __syncthreads();
  }
  boff[t] = s[t] - v;  // exclusive
}
__global__ __launch_bounds__(256) void apply_kernel(
    const int* __restrict__ cnt, const int* __restrict__ boff,
    int* __restrict__ rowptr, float* __restrict__ invdeg) {
  __shared__ int s[256];
  int t = threadIdx.x;
  int i = blockIdx.x * 256 + t;
  int v = (i < Nn) ? cnt[i] : 0;
  s[t] = v;
  __syncthreads();
  for (int off = 1; off < 256; off <<= 1) {
    int x = (t >= off) ? s[t - off] : 0;
    __syncthreads();
    s[t] += x;
    __syncthreads();
  }
  int ex = boff[blockIdx.x] + s[t] - v;
  if (i < Nn) {
    rowptr[i] = ex;
    invdeg[i] = 1.0f / fmaxf((float)v, 1.0f);
    if (i == Nn - 1) rowptr[Nn] = ex + v;
  }
}
// p2b: per-bucket final scatter into CSR span (writes stay in ~26KB L2-local region)
__global__ __launch_bounds__(256) void bkt_fin(
    const int* __restrict__ bktbase, const int2* __restrict__ recA,
    const unsigned char* __restrict__ dlo, const int* __restrict__ rowptr,
    int2* __restrict__ rec) {
  __shared__ int cur[256];
  int t = threadIdx.x;
  int b = blockIdx.x;
  int d = b * 256 + t;
  cur[t] = (d < Nn) ? rowptr[d] : 0;
  __syncthreads();
  int lo = bktbase[b], hi = bktbase[b + 1];
  for (int i = lo + t; i < hi; i += 256) {
    int dl = dlo[i];
    int p = atomicAdd(&cur[dl], 1);
    rec[p] = recA[i];
  }
}

// gb_static[g] = xbc[g] @ Wu[384:512] + bu
__global__ __launch_bounds__(128) void gb_static_kernel(
    const float* __restrict__ bcsum, const float* __restrict__ bccnt,
    const float* __restrict__ Wu, const float* __restrict__ bu,
    float* __restrict__ gbst) {
  __shared__ float xb[128];
  int g = blockIdx.x, t = threadIdx.x;
  xb[t] = bcsum[g * 128 + t] / fmaxf(bccnt[g], 1.f);
  __syncthreads();
  float acc = bu[t];
#pragma unroll 4
  for (int k = 0; k < 128; k++) acc = fmaf(xb[k], Wu[(size_t)(384 + k) * 128 + t], acc);
  gbst[g * 128 + t] = acc;
}

// gb[g] = gb_static[g] + xg[g] @ Wu[256:384]
__global__ __launch_bounds__(128) void gb_dyn_kernel(
    const float* __restrict__ gsum, const float* __restrict__ gcnt,
    const float* __restrict__ gbst, const float* __restrict__ Wu,
    float* __restrict__ gb) {
  __shared__ float xg[128];
  int g = blockIdx.x, t = threadIdx.x;
  xg[t] = gsum[g * 128 + t] / fmaxf(gcnt[g], 1.f);
  __syncthreads();
  float acc = gbst[g * 128 + t];
#pragma unroll 4
  for (int k = 0; k < 128; k++) acc = fmaf(xg[k], Wu[(size_t)(256 + k) * 128 + t], acc);
  gb[g * 128 + t] = acc;
}

// ---------------------------------------------------------------- proj (MFMA split-bf16)
// blockIdx.y==0: hs8 (fp8 e4m3) = h @ Wm[0:128]
// blockIdx.y==1: hdbf (bf16)    = h @ Wm[128:256]
__global__ __launch_bounds__(256) void proj_mfma(
    const float* __restrict__ h, const short* __restrict__ Wth,
    const short* __restrict__ Wtl, unsigned char* __restrict__ hs8,
    unsigned short* __restrict__ hdbf) {
  __shared__ short Ah_s[128 * AP], Al_s[128 * AP];
  __shared__ short Bh_s[128 * AP], Bl_s[128 * AP];
  const int t = threadIdx.x;
  const int nBase = blockIdx.x * 128;
  const int yoff = blockIdx.y * 16384;
  const int wave = t >> 6, lane = t & 63;
  const int ml = lane & 15, quad = lane >> 4;
  const int ko = quad * 8;

  f32x4 acc[2][8];
#pragma unroll
  for (int nt = 0; nt < 2; nt++)
#pragma unroll
    for (int mt = 0; mt < 8; mt++)
#pragma unroll
      for (int q = 0; q < 4; q++) acc[nt][mt][q] = 0.f;

  const int srow = t >> 1;
  const int kc = (t & 1) * 16;
  const int nd0 = nBase + srow;
  const int nn = nd0 < Nn ? nd0 : Nn - 1;

  for (int c = 0; c < 4; c++) {
    const float* p = &h[(size_t)nn * 128 + c * 32 + kc];
    float4 u0 = *(const float4*)(p + 0);
    float4 u1 = *(const float4*)(p + 4);
    float4 u2 = *(const float4*)(p + 8);
    float4 u3 = *(const float4*)(p + 12);
    const int k0 = c * 32;
    const bf16x8 gb0 = *(const bf16x8*)&Wth[(size_t)yoff + srow * 128 + k0 + kc];
    const bf16x8 gb1 = *(const bf16x8*)&Wth[(size_t)yoff + srow * 128 + k0 + kc + 8];
    const bf16x8 gl0 = *(const bf16x8*)&Wtl[(size_t)yoff + srow * 128 + k0 + kc];
    const bf16x8 gl1 = *(const bf16x8*)&Wtl[(size_t)yoff + srow * 128 + k0 + kc + 8];
    float xs[16] = {u0.x,u0.y,u0.z,u0.w, u1.x,u1.y,u1.z,u1.w,
                    u2.x,u2.y,u2.z,u2.w, u3.x,u3.y,u3.z,u3.w};
    bf16x8 vh0, vh1, vl0, vl1;
#pragma unroll
    for (int j = 0; j < 8; j++) {
      short hi = f2bf(xs[j]);
      vh0[j] = hi; vl0[j] = f2bf(xs[j] - bf2f(hi));
    }
#pragma unroll
    for (int j = 0; j < 8; j++) {
      short hi = f2bf(xs[8 + j]);
      vh1[j] = hi; vl1[j] = f2bf(xs[8 + j] - bf2f(hi));
    }
    __syncthreads();
    *(bf16x8*)&Ah_s[srow * AP + kc] = vh0;
    *(bf16x8*)&Ah_s[srow * AP + kc + 8] = vh1;
    *(bf16x8*)&Al_s[srow * AP + kc] = vl0;
    *(bf16x8*)&Al_s[srow * AP + kc + 8] = vl1;
    *(bf16x8*)&Bh_s[srow * AP + kc] = gb0;
    *(bf16x8*)&Bh_s[srow * AP + kc + 8] = gb1;
    *(bf16x8*)&Bl_s[srow * AP + kc] = gl0;
    *(bf16x8*)&Bl_s[srow * AP + kc + 8] = gl1;
    __syncthreads();
#pragma unroll
    for (int mt = 0; mt < 8; mt++) {
      const int ar = (mt * 16 + ml) * AP + ko;
      bf16x8 ah = *(const bf16x8*)&Ah_s[ar];
      bf16x8 al = *(const bf16x8*)&Al_s[ar];
#pragma unroll
      for (int nt = 0; nt < 2; nt++) {
        const int br = (wave * 32 + nt * 16 + ml) * AP + ko;
        bf16x8 bh = *(const bf16x8*)&Bh_s[br];
        bf16x8 bl = *(const bf16x8*)&Bl_s[br];
        acc[nt][mt] = __builtin_amdgcn_mfma_f32_16x16x32_bf16(ah, bh, acc[nt][mt], 0, 0, 0);
        acc[nt][mt] = __builtin_amdgcn_mfma_f32_16x16x32_bf16(ah, bl, acc[nt][mt], 0, 0, 0);
        acc[nt][mt] = __builtin_amdgcn_mfma_f32_16x16x32_bf16(al, bh, acc[nt][mt], 0, 0, 0);
      }
    }
  }
  if (blockIdx.y == 0) {
#pragma unroll
    for (int nt = 0; nt < 2; nt++) {
      const int ch = wave * 32 + nt * 16 + ml;
#pragma unroll
      for (int mt = 0; mt < 8; mt++) {
#pragma unroll
        for (int q = 0; q < 4; q++) {
          int nd = nBase + mt * 16 + quad * 4 + q;
          if (nd < Nn) {
            int pk = __builtin_amdgcn_cvt_pk_fp8_f32(acc[nt][mt][q], acc[nt][mt][q], 0, false);
            hs8[(size_t)nd * 128 + ch] = (unsigned char)(pk & 0xff);
          }
        }
      }
    }
  } else {
#pragma unroll
    for (int nt = 0; nt < 2; nt++) {
      const int ch = wave * 32 + nt * 16 + ml;
#pragma unroll
      for (int mt = 0; mt < 8; mt++) {
#pragma unroll
        for (int q = 0; q < 4; q++) {
          int nd = nBase + mt * 16 + quad * 4 + q;
          if (nd < Nn) hdbf[(size_t)nd * 128 + ch] = (unsigned short)f2bf(acc[nt][mt][q]);
        }
      }
    }
  }
}

// ---------------------------------------------------------------- edge pass / aggregation
__global__ __launch_bounds__(256) void agg_kernel(
    const unsigned char* __restrict__ hs8, const unsigned short* __restrict__ hdbf,
    unsigned short* __restrict__ aggbf, const int2* __restrict__ rec,
    const int* __restrict__ rowptr, const float* __restrict__ invdeg,
    const float* __restrict__ Wm, const float* __restrict__ bm) {
  int t = threadIdx.x;
  int hw = t >> 5, lane = t & 31;
  int v = blockIdx.x * 8 + hw;
  if (v >= Nn) return;
  int c0 = lane * 4;
  const float4 We0 = *(const float4*)&Wm[(size_t)256 * 128 + c0];
  const float4 We1 = *(const float4*)&Wm[(size_t)257 * 128 + c0];
  const float4 We2 = *(const float4*)&Wm[(size_t)258 * 128 + c0];
  const float4 b4  = *(const float4*)&bm[c0];
  const ushort4 hd4 = *(const ushort4*)&hdbf[(size_t)v * 128 + c0];
  const float bx = b4.x + bf2f((short)hd4.x), by = b4.y + bf2f((short)hd4.y),
              bz = b4.z + bf2f((short)hd4.z), bw = b4.w + bf2f((short)hd4.w);
  float ax = 0.f, ay = 0.f, az = 0.f, aw = 0.f;
  float ax2 = 0.f, ay2 = 0.f, az2 = 0.f, aw2 = 0.f;
  const int r0 = rowptr[v], r1 = rowptr[v + 1];
  int e = r0;
  for (; e + 2 <= r1; e += 2) {
    int2 q0 = rec[e], q1 = rec[e + 1];
    int s0 = q0.x & 0xffff, s1 = q1.x & 0xffff;
    unsigned hr0 = *(const unsigned*)&hs8[(size_t)s0 * 128 + c0];
    unsigned hr1 = *(const unsigned*)&hs8[(size_t)s1 * 128 + c0];
    float e00 = bf2f((short)(q0.x >> 16));
    float e01 = bf2f((short)(q0.y & 0xffff));
    float e02 = bf2f((short)(q0.y >> 16));
    float e10 = bf2f((short)(q1.x >> 16));
    float e11 = bf2f((short)(q1.y & 0xffff));
    float e12 = bf2f((short)(q1.y >> 16));
    float h0x = __builtin_amdgcn_cvt_f32_fp8(hr0, 0);
    float h0y = __builtin_amdgcn_cvt_f32_fp8(hr0, 1);
    float h0z = __builtin_amdgcn_cvt_f32_fp8(hr0, 2);
    float h0w = __builtin_amdgcn_cvt_f32_fp8(hr0, 3);
    float h1x = __builtin_amdgcn_cvt_f32_fp8(hr1, 0);
    float h1y = __builtin_amdgcn_cvt_f32_fp8(hr1, 1);
    float h1z = __builtin_amdgcn_cvt_f32_fp8(hr1, 2);
    float h1w = __builtin_amdgcn_cvt_f32_fp8(hr1, 3);
    ax += fmaxf(fmaf(e00, We0.x, fmaf(e01, We1.x, fmaf(e02, We2.x, h0x + bx))), 0.f);
    ay += fmaxf(fmaf(e00, We0.y, fmaf(e01, We1.y, fmaf(e02, We2.y, h0y + by))), 0.f);
    az += fmaxf(fmaf(e00, We0.z, fmaf(e01, We1.z, fmaf(e02, We2.z, h0z + bz))), 0.f);
    aw += fmaxf(fmaf(e00, We0.w, fmaf(e01, We1.w, fmaf(e02, We2.w, h0w + bw))), 0.f);
    ax2 += fmaxf(fmaf(e10, We0.x, fmaf(e11, We1.x, fmaf(e12, We2.x, h1x + bx))), 0.f);
    ay2 += fmaxf(fmaf(e10, We0.y, fmaf(e11, We1.y, fmaf(e12, We2.y, h1y + by))), 0.f);
    az2 += fmaxf(fmaf(e10, We0.z, fmaf(e11, We1.z, fmaf(e12, We2.z, h1z + bz))), 0.f);
    aw2 += fmaxf(fmaf(e10, We0.w, fmaf(e11, We1.w, fmaf(e12, We2.w, h1w + bw))), 0.f);
  }
  if (e < r1) {
    int2 q0 = rec[e];
    int s0 = q0.x & 0xffff;
    unsigned hr0 = *(const unsigned*)&hs8[(size_t)s0 * 128 + c0];
    float e00 = bf2f((short)(q0.x >> 16));
    float e01 = bf2f((short)(q0.y & 0xffff));
    float e02 = bf2f((short)(q0.y >> 16));
    float h0x = __builtin_amdgcn_cvt_f32_fp8(hr0, 0);
    float h0y = __builtin_amdgcn_cvt_f32_fp8(hr0, 1);
    float h0z = __builtin_amdgcn_cvt_f32_fp8(hr0, 2);
    float h0w = __builtin_amdgcn_cvt_f32_fp8(hr0, 3);
    ax += fmaxf(fmaf(e00, We0.x, fmaf(e01, We1.x, fmaf(e02, We2.x, h0x + bx))), 0.f);
    ay += fmaxf(fmaf(e00, We0.y, fmaf(e01, We1.y, fmaf(e02, We2.y, h0y + by))), 0.f);
    az += fmaxf(fmaf(e00, We0.z, fmaf(e01, We1.z, fmaf(e02, We2.z, h0z + bz))), 0.f);
    aw += fmaxf(fmaf(e00, We0.w, fmaf(e01, We1.w, fmaf(e02, We2.w, h0w + bw))), 0.f);
  }
  const float idg = invdeg[v];
  ushort4 o;
  o.x = (unsigned short)f2bf((ax + ax2) * idg);
  o.y = (unsigned short)f2bf((ay + ay2) * idg);
  o.z = (unsigned short)f2bf((az + az2) * idg);
  o.w = (unsigned short)f2bf((aw + aw2) * idg);
  *(ushort4*)&aggbf[(size_t)v * 128 + c0] = o;
}

// ---------------------------------------------------------------- update (MFMA split-bf16) + fused group-sum
__global__ __launch_bounds__(256) void updg_mfma(
    float* __restrict__ h, const unsigned short* __restrict__ aggbf,
    const int* __restrict__ batch,
    const short* __restrict__ Wth, const short* __restrict__ Wtl,
    const float* __restrict__ gb, float* __restrict__ gsum_out) {
  __shared__ short Ah_s[128 * AP], Al_s[128 * AP];
  __shared__ short Bh_s[128 * AP], Bl_s[128 * AP];
  __shared__ float gbs[Bb * 128];
  __shared__ float ls[Bb * 128];
  const int t = threadIdx.x;
  const int nBase = blockIdx.x * 128;
  *(float4*)&gbs[t * 4] = *(const float4*)&gb[t * 4];
#pragma unroll
  for (int q = 0; q < 4; q++) ls[t + q * 256] = 0.f;

  const int wave = t >> 6, lane = t & 63;
  const int ml = lane & 15, quad = lane >> 4;
  const int ko = quad * 8;

  f32x4 acc[2][8];
#pragma unroll
  for (int nt = 0; nt < 2; nt++)
#pragma unroll
    for (int mt = 0; mt < 8; mt++)
#pragma unroll
      for (int q = 0; q < 4; q++) acc[nt][mt][q] = 0.f;

  const int srow = t >> 1;
  const int kc = (t & 1) * 16;
  const int nd0 = nBase + srow;
  const int nn = nd0 < Nn ? nd0 : Nn - 1;

  for (int c = 0; c < 8; c++) {
    const int k0 = c * 32;
    bf16x8 vh0, vh1, vl0, vl1;
    if (c < 4) {
      const float* p = &h[(size_t)nn * 128 + c * 32 + kc];
      float4 u0 = *(const float4*)(p + 0);
      float4 u1 = *(const float4*)(p + 4);
      float4 u2 = *(const float4*)(p + 8);
      float4 u3 = *(const float4*)(p + 12);
      float xs[16] = {u0.x,u0.y,u0.z,u0.w, u1.x,u1.y,u1.z,u1.w,
                      u2.x,u2.y,u2.z,u2.w, u3.x,u3.y,u3.z,u3.w};
#pragma unroll
      for (int j = 0; j < 8; j++) {
        short hi = f2bf(xs[j]);
        vh0[j] = hi; vl0[j] = f2bf(xs[j] - bf2f(hi));
      }
#pragma unroll
      for (int j = 0; j < 8; j++) {
        short hi = f2bf(xs[8 + j]);
        vh1[j] = hi; vl1[j] = f2bf(xs[8 + j] - bf2f(hi));
      }
    } else {
      const unsigned short* pa = &aggbf[(size_t)nn * 128 + (c - 4) * 32 + kc];
      vh0 = *(const bf16x8*)(pa);
      vh1 = *(const bf16x8*)(pa + 8);
    }
    const bf16x8 gb0 = *(const bf16x8*)&Wth[(size_t)srow * 256 + k0 + kc];
    const bf16x8 gb1 = *(const bf16x8*)&Wth[(size_t)srow * 256 + k0 + kc + 8];
    const bf16x8 gl0 = *(const bf16x8*)&Wtl[(size_t)srow * 256 + k0 + kc];
    const bf16x8 gl1 = *(const bf16x8*)&Wtl[(size_t)srow * 256 + k0 + kc + 8];
    __syncthreads();
    *(bf16x8*)&Ah_s[srow * AP + kc] = vh0;
    *(bf16x8*)&Ah_s[srow * AP + kc + 8] = vh1;
    if (c < 4) {
      *(bf16x8*)&Al_s[srow * AP + kc] = vl0;
      *(bf16x8*)&Al_s[srow * AP + kc + 8] = vl1;
    }
    *(bf16x8*)&Bh_s[srow * AP + kc] = gb0;
    *(bf16x8*)&Bh_s[srow * AP + kc + 8] = gb1;
    *(bf16x8*)&Bl_s[srow * AP + kc] = gl0;
    *(bf16x8*)&Bl_s[srow * AP + kc + 8] = gl1;
    __syncthreads();
    if (c < 4) {
#pragma unroll
      for (int mt = 0; mt < 8; mt++) {
        const int ar = (mt * 16 + ml) * AP + ko;
        bf16x8 ah = *(const bf16x8*)&Ah_s[ar];
        bf16x8 al = *(const bf16x8*)&Al_s[ar];
#pragma unroll
        for (int nt = 0; nt < 2; nt++) {
          const int br = (wave * 32 + nt * 16 + ml) * AP + ko;
          bf16x8 bh = *(const bf16x8*)&Bh_s[br];
          bf16x8 bl = *(const bf16x8*)&Bl_s[br];
          acc[nt][mt] = __builtin_amdgcn_mfma_f32_16x16x32_bf16(ah, bh, acc[nt][mt], 0, 0, 0);
          acc[nt][mt] = __builtin_amdgcn_mfma_f32_16x16x32_bf16(ah, bl, acc[nt][mt], 0, 0, 0);
          acc[nt][mt] = __builtin_amdgcn_mfma_f32_16x16x32_bf16(al, bh, acc[nt][mt], 0, 0, 0);
        }
      }
    } else {
#pragma unroll
      for (int mt = 0; mt < 8; mt++) {
        const int ar = (mt * 16 + ml) * AP + ko;
        bf16x8 ah = *(const bf16x8*)&Ah_s[ar];
#pragma unroll
        for (int nt = 0; nt < 2; nt++) {
          const int br = (wave * 32 + nt * 16 + ml) * AP + ko;
          bf16x8 bh = *(const bf16x8*)&Bh_s[br];
          bf16x8 bl = *(const bf16x8*)&Bl_s[br];
          acc[nt][mt] = __builtin_amdgcn_mfma_f32_16x16x32_bf16(ah, bh, acc[nt][mt], 0, 0, 0);
          acc[nt][mt] = __builtin_amdgcn_mfma_f32_16x16x32_bf16(ah, bl, acc[nt][mt], 0, 0, 0);
        }
      }
    }
  }
#pragma unroll
  for (int nt = 0; nt < 2; nt++) {
    const int ch = wave * 32 + nt * 16 + ml;
#pragma unroll
    for (int mt = 0; mt < 8; mt++) {
      int rbase = nBase + mt * 16 + quad * 4;
      float runv = 0.f;
      int curb = -1;
#pragma unroll
      for (int q = 0; q < 4; q++) {
        int nd = rbase + q;
        if (nd < Nn) {
          int bi = batch[nd];
          float u = fmaxf(acc[nt][mt][q] + gbs[bi * 128 + ch], 0.f);
          float hn = h[(size_t)nd * 128 + ch] + u;
          h[(size_t)nd * 128 + ch] = hn;
          if (bi != curb) {
            if (curb >= 0) atomicAdd(&ls[curb * 128 + ch], runv);
            curb = bi;
            runv = 0.f;
          }
          runv += hn;
        }
      }
      if (curb >= 0) atomicAdd(&ls[curb * 128 + ch], runv);
    }
  }
  __syncthreads();
#pragma unroll
  for (int q = 0; q < 4; q++) {
    int idx = t + q * 256;
    float v = ls[idx];
    if (v != 0.f) atomicAdd(&gsum_out[idx], v);
  }
}

// ---------------------------------------------------------------- kwv (MFMA bf16) + fused decode
__global__ __launch_bounds__(256) void kwv_kernel(
    const float* __restrict__ h, const float* __restrict__ pos,
    const float* __restrict__ Fm, const float* __restrict__ Wd,
    const float* __restrict__ bd, float* __restrict__ partial,
    float* __restrict__ ksum, float* __restrict__ out) {
  __shared__ float h_s[32 * HP];     // fp32 tile for decode
  __shared__ short nkT[128 * KS];    // A: nkT[m][k]
  __shared__ short hT[128 * KS];     // B: hT[n][k]
  __shared__ float wd[512];
  __shared__ float ksum_s[128];
  const int t = threadIdx.x;
  const int hr = t >> 3;
  const int hc = (t & 7) * 16;
  const int fg = (t & 7) * 8;
  const int wave = t >> 6, lane = t & 63;
  const int ml = lane & 15, quad = lane >> 4;
  const int ko = quad * 8;
  if (t < 128) { *(float4*)&wd[t * 4] = *(const float4*)&Wd[t * 4]; ksum_s[t] = 0.f; }
  const float bdv = bd[t & 3];
  f32x4 acc[2][8];
#pragma unroll
  for (int nt = 0; nt < 2; nt++)
#pragma unroll
    for (int mt = 0; mt < 8; mt++)
#pragma unroll
      for (int q = 0; q < 4; q++) acc[nt][mt][q] = 0.f;
  float klc[8], kls[8];
#pragma unroll
  for (int f = 0; f < 8; f++) { klc[f] = 0.f; kls[f] = 0.f; }

  const int nTiles = (Nn + 31) / 32;  // 1563
  for (int tile = blockIdx.x; tile < nTiles; tile += gridDim.x) {
    const int gh = tile * 32 + hr;
    float4 hv0 = {0.f, 0.f, 0.f, 0.f}, hv1 = hv0, hv2 = hv0, hv3 = hv0;
    float cbuf[8], sbuf[8];
    if (gh < Nn) {
      const float* hp = &h[(size_t)gh * 128 + hc];
      hv0 = *(const float4*)(hp + 0);
      hv1 = *(const float4*)(hp + 4);
      hv2 = *(const float4*)(hp + 8);
      hv3 = *(const float4*)(hp + 12);
      const float px = pos[gh * 2 + 0], py = pos[gh * 2 + 1];
#pragma unroll
      for (int f = 0; f < 8; f++) {
        float p = px * Fm[fg + f] + py * Fm[64 + fg + f];
        cbuf[f] = cosf(p) * 0.125f;
        sbuf[f] = sinf(p) * 0.125f;
      }
    } else {
#pragma unroll
      for (int f = 0; f < 8; f++) { cbuf[f] = 0.f; sbuf[f] = 0.f; }
    }
    float xs[16] = {hv0.x,hv0.y,hv0.z,hv0.w, hv1.x,hv1.y,hv1.z,hv1.w,
                    hv2.x,hv2.y,hv2.z,hv2.w, hv3.x,hv3.y,hv3.z,hv3.w};
    __syncthreads();
    *(float4*)&h_s[hr * HP + hc + 0]  = hv0;
    *(float4*)&h_s[hr * HP + hc + 4]  = hv1;
    *(float4*)&h_s[hr * HP + hc + 8]  = hv2;
    *(float4*)&h_s[hr * HP + hc + 12] = hv3;
#pragma unroll
    for (int i = 0; i < 16; i++) hT[(hc + i) * KS + hr] = f2bf(xs[i]);
#pragma unroll
    for (int f = 0; f < 8; f++) {
      nkT[(fg + f) * KS + hr] = f2bf(cbuf[f]);
      nkT[(64 + fg + f) * KS + hr] = f2bf(sbuf[f]);
      klc[f] += cbuf[f];
      kls[f] += sbuf[f];
    }
    __syncthreads();
#pragma unroll
    for (int mt = 0; mt < 8; mt++) {
      bf16x8 ah = *(const bf16x8*)&nkT[(mt * 16 + ml) * KS + ko];
#pragma unroll
      for (int nt = 0; nt < 2; nt++) {
        bf16x8 bh = *(const bf16x8*)&hT[(wave * 32 + nt * 16 + ml) * KS + ko];
        acc[nt][mt] = __builtin_amdgcn_mfma_f32_16x16x32_bf16(ah, bh, acc[nt][mt], 0, 0, 0);
      }
    }
    if (t < 128) {  // fused decode (fp32)
      int n = t >> 2, o = t & 3;
      int gn = tile * 32 + n;
      if (gn < Nn) {
        float s = bdv;
#pragma unroll 4
        for (int kk = 0; kk < 128; kk++) {
          int k = (kk + n) & 127;
          s = fmaf(h_s[n * HP + k], wd[k * 4 + o], s);
        }
        out[4 + (size_t)gn * 4 + o] = s;
      }
    }
  }
  float* pb = &partial[(size_t)blockIdx.x * 16384];
#pragma unroll
  for (int nt = 0; nt < 2; nt++) {
    const int col = wave * 32 + nt * 16 + ml;
#pragma unroll
    for (int mt = 0; mt < 8; mt++) {
#pragma unroll
      for (int q = 0; q < 4; q++) {
        int row = mt * 16 + quad * 4 + q;
        pb[row * 128 + col] = acc[nt][mt][q];
      }
    }
  }
#pragma unroll
  for (int f = 0; f < 8; f++) {
    atomicAdd(&ksum_s[fg + f], klc[f]);
    atomicAdd(&ksum_s[64 + fg + f], kls[f]);
  }
  __syncthreads();
  if (t < 128) atomicAdd(&ksum[t], ksum_s[t]);
}

__global__ __launch_bounds__(256) void kwv_reduce(const float* __restrict__ partial,
                                                  float* __restrict__ kwv) {
  int idx = blockIdx.x * 256 + threadIdx.x;
  float s = 0.f;
  for (int b = 0; b < KWVB; b++) s += partial[(size_t)b * 16384 + idx];
  kwv[idx] = s;
}

// ---------------------------------------------------------------- final sampling head
__global__ __launch_bounds__(128) void final_kernel(
    const float* __restrict__ sp, const float* __restrict__ Fm,
    const float* __restrict__ kwv, const float* __restrict__ vs,
    const float* __restrict__ ksum, const float* __restrict__ Wd,
    const float* __restrict__ bd, float* __restrict__ out) {
  __shared__ float nq_s[128];
  __shared__ float red[2];
  __shared__ float redU[8];
  int t = threadIdx.x;
  int jj = t & 63;
  float p = sp[0] * Fm[jj] + sp[1] * Fm[64 + jj];
  nq_s[t] = ((t < 64) ? cosf(p) : sinf(p)) * 0.125f;  // ||q||=sqrt(0.5) exact
  __syncthreads();
  float num = 0.f;
#pragma unroll
  for (int g = 0; g < Bb; g++) num += vs[g * 128 + t];
  for (int k = 0; k < 128; k++) num = fmaf(nq_s[k], kwv[k * 128 + t], num);
  float dp = nq_s[t] * ksum[t];
#pragma unroll
  for (int off = 32; off > 0; off >>= 1) dp += __shfl_down(dp, off);
  if ((t & 63) == 0) red[t >> 6] = dp;
  __syncthreads();
  float den = (float)Nn + red[0] + red[1];
  float e = num / den;
  float u[4];
#pragma unroll
  for (int o = 0; o < 4; o++) u[o] = e * Wd[t * 4 + o];
#pragma unroll
  for (int off = 32; off > 0; off >>= 1) {
#pragma unroll
    for (int o = 0; o < 4; o++) u[o] += __shfl_down(u[o], off);
  }
  if ((t & 63) == 0) {
#pragma unroll
    for (int o = 0; o < 4; o++) redU[(t >> 6) * 4 + o] = u[o];
  }
  __syncthreads();
  if (t < 4) out[t] = redU[t] + redU[4 + t] + bd[t];
}

// ---------------------------------------------------------------- launcher
extern "C" void kernel_launch(void* const* d_in, const int* in_sizes, int n_in,
                              void* d_out, int out_size, void* d_ws, size_t ws_size,
                              hipStream_t stream) {
  const float* x    = (const float*)d_in[0];
  const float* xm   = (const float*)d_in[1];
  const int*   ei   = (const int*)d_in[2];
  const float* ea   = (const float*)d_in[3];
  const float* pos  = (const float*)d_in[4];
  const int*   batch= (const int*)d_in[5];
  const float* sp   = (const float*)d_in[6];
  const float* Fm   = (const float*)d_in[7];
  const float* Wenc = (const float*)d_in[8];
  const float* benc = (const float*)d_in[9];
  const float* Wmsg = (const float*)d_in[10];
  const float* bmsg = (const float*)d_in[11];
  const float* Wupd = (const float*)d_in[12];
  const float* bupd = (const float*)d_in[13];
  const float* Wdec = (const float*)d_in[14];
  const float* bdec = (const float*)d_in[15];
  float* out = (float*)d_out;

  float* ws     = (float*)d_ws;
  float* h      = ws;                              // N*128
  float* agg    = h + (size_t)Nn * 128;            // region: aggbf (12.8MB); kwv partials span
  float* aux    = agg + (size_t)Nn * 128;          // region: hs8 (6.4MB) + hdbf (12.8MB)
  float* invdeg = aux + (size_t)Nn * 128;          // N
  // ---- zeroed region (6416 floats) ----
  float* gsum   = invdeg + Nn;                     // 1024
  float* gcnt   = gsum + 1024;                     // 8
  float* bcsum  = gcnt + 8;                        // 1024
  float* bccnt  = bcsum + 1024;                    // 8
  float* gsumR  = bccnt + 8;                       // 4*1024
  float* vsum   = gsumR + 4096;                    // 128 (unused)
  float* ksum   = vsum + 128;                      // 128
  // ---- end zeroed region ----
  float* gbst   = ksum + 128;                      // 1024
  float* gbuf   = gbst + 1024;                     // 4*1024
  float* kwv    = gbuf + 4096;                     // 16384
  int2*  rec    = (int2*)(kwv + 16384);            // E (packed 8B, CSR order)
  int*   cnt    = (int*)(rec + Ee);                // N
  int*   rowptr = cnt + Nn;                        // N+1
  int*   bsum   = rowptr + Nn + 1;                 // 256
  int*   boff   = bsum + 256;                      // 256
  int*   bktcnt = boff + 256;                      // 196 (zeroed)
  int*   bktbase= bktcnt + 196;                    // 197
  int*   bktcur = bktbase + 197;                   // 196
  short* wmt_h  = (short*)(bktcur + 196);          // 2*128*128
  short* wmt_l  = wmt_h + 32768;
  short* wut_h  = wmt_l + 32768;                   // 128*256
  short* wut_l  = wut_h + 32768;
  int2*  recA   = (int2*)(wut_l + 32768);          // E (bucket-partitioned staging)
  unsigned char* dlo = (unsigned char*)(recA + Ee);// E

  unsigned short* aggbf = (unsigned short*)agg;                     // 12.8 MB
  unsigned char*  hs8   = (unsigned char*)aux;                      // 6.4 MB
  unsigned short* hdbf  = (unsigned short*)(hs8 + (size_t)Nn * 128);// 12.8 MB

  hipMemsetAsync(gsum, 0, 6416 * sizeof(float), stream);
  hipMemsetAsync(bktcnt, 0, 196 * sizeof(int), stream);

  split_w_kernel<<<256, 256, 0, stream>>>(Wmsg, Wupd, wmt_h, wmt_l, wut_h, wut_l);

  // CSR build via 2-phase radix partition (all passes coalesced)
  bkt_cnt<<<P1B, 256, 0, stream>>>(ei, bktcnt);
  bkt_scan<<<1, 256, 0, stream>>>(bktcnt, bktbase, bktcur);
  bkt_part<<<P1B, 256, 0, stream>>>(ei, ea, bktcur, recA, dlo);
  dst_cnt<<<NBK, 256, 0, stream>>>(bktbase, dlo, cnt);
  bsum_kernel<<<SCB, 256, 0, stream>>>(cnt, bsum);
  scan_top_kernel<<<1, 256, 0, stream>>>(bsum, boff);
  apply_kernel<<<SCB, 256, 0, stream>>>(cnt, boff, rowptr, invdeg);
  bkt_fin<<<NBK, 256, 0, stream>>>(bktbase, recA, dlo, rowptr, rec);

  const int nb128 = (Nn + 127) / 128;  // 391
  encode_seg<<<nb128, 256, 0, stream>>>(x, xm, batch, Wenc, benc, h,
                                        gsum, gcnt, bcsum, bccnt);
  gb_static_kernel<<<Bb, 128, 0, stream>>>(bcsum, bccnt, Wupd, bupd, gbst);
  gb_dyn_kernel<<<Bb, 128, 0, stream>>>(gsum, gcnt, gbst, Wupd, gbuf);

  for (int r = 0; r < ROUNDS; r++) {
    proj_mfma<<<dim3(nb128, 2), 256, 0, stream>>>(h, wmt_h, wmt_l, hs8, hdbf);
    agg_kernel<<<(Nn + 7) / 8, 256, 0, stream>>>(hs8, hdbf, aggbf, rec, rowptr,
                                                 invdeg, Wmsg, bmsg);
    updg_mfma<<<nb128, 256, 0, stream>>>(h, aggbf, batch, wut_h, wut_l,
                                         gbuf + r * 1024, gsumR + r * 1024);
    if (r < ROUNDS - 1)
      gb_dyn_kernel<<<Bb, 128, 0, stream>>>(gsumR + r * 1024, gcnt, gbst, Wupd,
                                            gbuf + (r + 1) * 1024);
  }

  // kwv partials alias the (now free) agg+aux regions: 512*64KB = 33.5 MB < 51.2 MB
  kwv_kernel<<<KWVB, 256, 0, stream>>>(h, pos, Fm, Wdec, bdec, agg, ksum, out);
  kwv_reduce<<<64, 256, 0, stream>>>(agg, kwv);
  final_kernel<<<1, 128, 0, stream>>>(sp, Fm, kwv, gsumR + 3 * 1024, ksum,
                                      Wdec, bdec, out);
}

// Round 16
// 675.116 us; speedup vs baseline: 1.1257x; 1.0499x over previous
//
#include <hip/hip_runtime.h>
#include <math.h>

#define Nn 50000
#define Ee 800000
#define Bb 8
#define ROUNDS 4
#define KWVB 512            // kwv partial blocks (2/CU)
#define SCB 196             // scan blocks (196*256 = 50176 >= Nn)
#define AP 40               // MFMA LDS row stride in shorts (32 k + 8 pad)
#define HP 132              // kwv fp32 h_s row stride (128 + 4 pad)
#define KS 40               // kwv bf16 transposed row stride in shorts
#define NBK 196             // dst buckets (dst >> 8)
#define P1B 391             // partition blocks
#define CHUNK 2047          // edges per partition block (391*2047 >= Ee)

typedef __attribute__((ext_vector_type(8))) short bf16x8;
typedef __attribute__((ext_vector_type(4))) float f32x4;

__device__ inline short f2bf(float f) {
  union { float f; unsigned u; } v; v.f = f;
  unsigned r = v.u + 0x7fff + ((v.u >> 16) & 1);  // RNE
  return (short)(r >> 16);
}
__device__ inline float bf2f(short s) {
  union { float f; unsigned u; } v; v.u = ((unsigned)(unsigned short)s) << 16;
  return v.f;
}

// ---------------------------------------------------------------- encode + fused segmean
__global__ __launch_bounds__(256) void encode_seg(
    const float* __restrict__ x, const float* __restrict__ xm,
    const int* __restrict__ batch, const float* __restrict__ W,
    const float* __restrict__ b, float* __restrict__ h,
    float* __restrict__ gsum, float* __restrict__ gcnt,
    float* __restrict__ bcsum, float* __restrict__ bccnt) {
  __shared__ float xs5[128 * 5];
  __shared__ float xm3[128 * 3];
  __shared__ float ls[Bb * 128];
  __shared__ float lb[Bb * 128];
  __shared__ float lc[Bb], lbc[Bb];
  const int t = threadIdx.x;
  const int nBase = blockIdx.x * 128;
  const int j = t & 127, half = t >> 7;
  const int base5 = nBase * 5, base3 = nBase * 3;
  for (int q = t; q < 640; q += 256) xs5[q] = (base5 + q < Nn * 5) ? x[base5 + q] : 0.f;
  for (int q = t; q < 384; q += 256) xm3[q] = (base3 + q < Nn * 3) ? xm[base3 + q] : 0.f;
  for (int q = t; q < Bb * 128; q += 256) { ls[q] = 0.f; lb[q] = 0.f; }
  if (t < Bb) { lc[t] = 0.f; lbc[t] = 0.f; }
  float Wcol[8];
#pragma unroll
  for (int k = 0; k < 8; k++) Wcol[k] = W[k * 128 + j];
  const float bj = b[j];
  __syncthreads();
  int curb = -1;
  float runh = 0.f, runb = 0.f, runc = 0.f, runbc = 0.f;
  for (int kk = 0; kk < 64; kk++) {
    int i = nBase + kk * 2 + half;
    if (i >= Nn) break;
    int li = i - nBase;
    float acc = bj;
#pragma unroll
    for (int k = 0; k < 5; k++) acc = fmaf(xs5[li * 5 + k], Wcol[k], acc);
#pragma unroll
    for (int k = 0; k < 3; k++) acc = fmaf(xm3[li * 3 + k], Wcol[5 + k], acc);
    float v = fmaxf(acc, 0.f);
    h[(size_t)i * 128 + j] = v;
    float bc = xm3[li * 3 + 2];
    int g = batch[i];
    if (g != curb) {
      if (curb >= 0) {
        atomicAdd(&ls[curb * 128 + j], runh);
        atomicAdd(&lb[curb * 128 + j], runb);
        if (j == 0) { atomicAdd(&lc[curb], runc); atomicAdd(&lbc[curb], runbc); }
      }
      curb = g; runh = runb = runc = runbc = 0.f;
    }
    runh += v; runb += v * bc;
    if (j == 0) { runc += 1.f; runbc += bc; }
  }
  if (curb >= 0) {
    atomicAdd(&ls[curb * 128 + j], runh);
    atomicAdd(&lb[curb * 128 + j], runb);
    if (j == 0) { atomicAdd(&lc[curb], runc); atomicAdd(&lbc[curb], runbc); }
  }
  __syncthreads();
  for (int q = t; q < Bb * 128; q += 256) {
    float a = ls[q], c = lb[q];
    if (a != 0.f) atomicAdd(&gsum[q], a);
    if (c != 0.f) atomicAdd(&bcsum[q], c);
  }
  if (t < Bb) { atomicAdd(&gcnt[t], lc[t]); atomicAdd(&bccnt[t], lbc[t]); }
}

// ---------------------------------------------------------------- weight split (once per launch)
__global__ __launch_bounds__(256) void split_w_kernel(
    const float* __restrict__ Wm, const float* __restrict__ Wu,
    short* __restrict__ Wmt_h, short* __restrict__ Wmt_l,
    short* __restrict__ Wut_h, short* __restrict__ Wut_l) {
  int idx = blockIdx.x * 256 + threadIdx.x;
  if (idx < 32768) {
    int k = idx & 127, n = (idx >> 7) & 127, y = idx >> 14;
    float w = Wm[(size_t)(y * 128 + k) * 128 + n];
    short hi = f2bf(w);
    Wmt_h[idx] = hi;
    Wmt_l[idx] = f2bf(w - bf2f(hi));
  } else if (idx < 65536) {
    int j = idx - 32768;
    int k = j & 255, n = j >> 8;
    float w = Wu[(size_t)k * 128 + n];
    short hi = f2bf(w);
    Wut_h[j] = hi;
    Wut_l[j] = f2bf(w - bf2f(hi));
  }
}

// ---------------------------------------------------------------- CSR build (radix partition)
__global__ __launch_bounds__(256) void bkt_cnt(const int* __restrict__ ei,
                                               int* __restrict__ bktcnt) {
  __shared__ int hist[NBK];
  int t = threadIdx.x;
  for (int q = t; q < NBK; q += 256) hist[q] = 0;
  __syncthreads();
  int base = blockIdx.x * CHUNK;
  int end = base + CHUNK < Ee ? base + CHUNK : Ee;
  for (int e = base + t; e < end; e += 256) atomicAdd(&hist[ei[Ee + e] >> 8], 1);
  __syncthreads();
  for (int q = t; q < NBK; q += 256)
    if (hist[q]) atomicAdd(&bktcnt[q], hist[q]);
}
__global__ __launch_bounds__(256) void bkt_scan(const int* __restrict__ bktcnt,
                                                int* __restrict__ bktbase,
                                                int* __restrict__ bktcur) {
  __shared__ int s[256];
  int t = threadIdx.x;
  int v = (t < NBK) ? bktcnt[t] : 0;
  s[t] = v;
  __syncthreads();
  for (int off = 1; off < 256; off <<= 1) {
    int x = (t >= off) ? s[t - off] : 0;
    __syncthreads();
    s[t] += x;
    __syncthreads();
  }
  int ex = s[t] - v;
  if (t < NBK) { bktbase[t] = ex; bktcur[t] = ex; }
  if (t == NBK - 1) bktbase[NBK] = ex + v;
}
__global__ __launch_bounds__(256) void bkt_part(
    const int* __restrict__ ei, const float* __restrict__ ea,
    int* __restrict__ bktcur, int2* __restrict__ recA,
    unsigned char* __restrict__ dlo) {
  __shared__ int hist[NBK], lbase[NBK], lcur[NBK];
  int t = threadIdx.x;
  for (int q = t; q < NBK; q += 256) hist[q] = 0;
  __syncthreads();
  int base = blockIdx.x * CHUNK;
  int end = base + CHUNK < Ee ? base + CHUNK : Ee;
  for (int e = base + t; e < end; e += 256) atomicAdd(&hist[ei[Ee + e] >> 8], 1);
  __syncthreads();
  for (int q = t; q < NBK; q += 256) {
    int c = hist[q];
    lbase[q] = c ? atomicAdd(&bktcur[q], c) : 0;
    lcur[q] = 0;
  }
  __syncthreads();
  for (int e = base + t; e < end; e += 256) {
    int d = ei[Ee + e];
    int bk = d >> 8;
    int p = lbase[bk] + atomicAdd(&lcur[bk], 1);
    unsigned r0 = (unsigned)ei[e] |
                  ((unsigned)(unsigned short)f2bf(ea[3 * (size_t)e + 0]) << 16);
    unsigned r1 = (unsigned)(unsigned short)f2bf(ea[3 * (size_t)e + 1]) |
                  ((unsigned)(unsigned short)f2bf(ea[3 * (size_t)e + 2]) << 16);
    recA[p] = make_int2((int)r0, (int)r1);
    dlo[p] = (unsigned char)(d & 255);
  }
}
__global__ __launch_bounds__(256) void dst_cnt(const int* __restrict__ bktbase,
                                               const unsigned char* __restrict__ dlo,
                                               int* __restrict__ cnt) {
  __shared__ int hh[256];
  int t = threadIdx.x;
  hh[t] = 0;
  __syncthreads();
  int b = blockIdx.x;
  int lo = bktbase[b], hi = bktbase[b + 1];
  for (int i = lo + t; i < hi; i += 256) atomicAdd(&hh[dlo[i]], 1);
  __syncthreads();
  int d = b * 256 + t;
  if (d < Nn) cnt[d] = hh[t];
}
__global__ __launch_bounds__(256) void bsum_kernel(const int* __restrict__ cnt,
                                                   int* __restrict__ bsum) {
  __shared__ int wsum[4];
  int t = threadIdx.x;
  int i = blockIdx.x * 256 + t;
  int v = (i < Nn) ? cnt[i] : 0;
#pragma unroll
  for (int off = 32; off > 0; off >>= 1) v += __shfl_down(v, off);
  if ((t & 63) == 0) wsum[t >> 6] = v;
  __syncthreads();
  if (t == 0) bsum[blockIdx.x] = wsum[0] + wsum[1] + wsum[2] + wsum[3];
}
__global__ __launch_bounds__(256) void scan_top_kernel(const int* __restrict__ bsum,
                                                       int* __restrict__ boff) {
  __shared__ int s[256];
  int t = threadIdx.x;
  int v = (t < SCB) ? bsum[t] : 0;
  s[t] = v;
  __syncthreads();
  for (int off = 1; off < 256; off <<= 1) {
    int x = (t >= off) ? s[t - off] : 0;
    __syncthreads();
    s[t] += x;
    __syncthreads();
  }
  boff[t] = s[t] - v;  // exclusive
}
__global__ __launch_bounds__(256) void apply_kernel(
    const int* __restrict__ cnt, const int* __restrict__ boff,
    int* __restrict__ rowptr, float* __restrict__ invdeg) {
  __shared__ int s[256];
  int t = threadIdx.x;
  int i = blockIdx.x * 256 + t;
  int v = (i < Nn) ? cnt[i] : 0;
  s[t] = v;
  __syncthreads();
  for (int off = 1; off < 256; off <<= 1) {
    int x = (t >= off) ? s[t - off] : 0;
    __syncthreads();
    s[t] += x;
    __syncthreads();
  }
  int ex = boff[blockIdx.x] + s[t] - v;
  if (i < Nn) {
    rowptr[i] = ex;
    invdeg[i] = 1.0f / fmaxf((float)v, 1.0f);
    if (i == Nn - 1) rowptr[Nn] = ex + v;
  }
}
__global__ __launch_bounds__(256) void bkt_fin(
    const int* __restrict__ bktbase, const int2* __restrict__ recA,
    const unsigned char* __restrict__ dlo, const int* __restrict__ rowptr,
    int2* __restrict__ rec) {
  __shared__ int cur[256];
  int t = threadIdx.x;
  int b = blockIdx.x;
  int d = b * 256 + t;
  cur[t] = (d < Nn) ? rowptr[d] : 0;
  __syncthreads();
  int lo = bktbase[b], hi = bktbase[b + 1];
  for (int i = lo + t; i < hi; i += 256) {
    int dl = dlo[i];
    int p = atomicAdd(&cur[dl], 1);
    rec[p] = recA[i];
  }
}

// gb_static[g] = xbc[g] @ Wu[384:512] + bu
__global__ __launch_bounds__(128) void gb_static_kernel(
    const float* __restrict__ bcsum, const float* __restrict__ bccnt,
    const float* __restrict__ Wu, const float* __restrict__ bu,
    float* __restrict__ gbst) {
  __shared__ float xb[128];
  int g = blockIdx.x, t = threadIdx.x;
  xb[t] = bcsum[g * 128 + t] / fmaxf(bccnt[g], 1.f);
  __syncthreads();
  float acc = bu[t];
#pragma unroll 4
  for (int k = 0; k < 128; k++) acc = fmaf(xb[k], Wu[(size_t)(384 + k) * 128 + t], acc);
  gbst[g * 128 + t] = acc;
}

// gb[g] = gb_static[g] + xg[g] @ Wu[256:384]
__global__ __launch_bounds__(128) void gb_dyn_kernel(
    const float* __restrict__ gsum, const float* __restrict__ gcnt,
    const float* __restrict__ gbst, const float* __restrict__ Wu,
    float* __restrict__ gb) {
  __shared__ float xg[128];
  int g = blockIdx.x, t = threadIdx.x;
  xg[t] = gsum[g * 128 + t] / fmaxf(gcnt[g], 1.f);
  __syncthreads();
  float acc = gbst[g * 128 + t];
#pragma unroll 4
  for (int k = 0; k < 128; k++) acc = fmaf(xg[k], Wu[(size_t)(256 + k) * 128 + t], acc);
  gb[g * 128 + t] = acc;
}

// ---------------------------------------------------------------- proj (MFMA single-bf16)
// Both outputs are quantized (fp8 / bf16), so hi-only bf16 inputs suffice:
// 1 MFMA per fragment (was 3), half the LDS, no lo-split VALU.
// blockIdx.y==0: hs8 (fp8 e4m3) = h @ Wm[0:128]
// blockIdx.y==1: hdbf (bf16)    = h @ Wm[128:256]
__global__ __launch_bounds__(256) void proj_mfma(
    const float* __restrict__ h, const short* __restrict__ Wth,
    unsigned char* __restrict__ hs8, unsigned short* __restrict__ hdbf) {
  __shared__ short Ah_s[128 * AP];
  __shared__ short Bh_s[128 * AP];
  const int t = threadIdx.x;
  const int nBase = blockIdx.x * 128;
  const int yoff = blockIdx.y * 16384;
  const int wave = t >> 6, lane = t & 63;
  const int ml = lane & 15, quad = lane >> 4;
  const int ko = quad * 8;

  f32x4 acc[2][8];
#pragma unroll
  for (int nt = 0; nt < 2; nt++)
#pragma unroll
    for (int mt = 0; mt < 8; mt++)
#pragma unroll
      for (int q = 0; q < 4; q++) acc[nt][mt][q] = 0.f;

  const int srow = t >> 1;
  const int kc = (t & 1) * 16;
  const int nd0 = nBase + srow;
  const int nn = nd0 < Nn ? nd0 : Nn - 1;

  for (int c = 0; c < 4; c++) {
    const float* p = &h[(size_t)nn * 128 + c * 32 + kc];
    float4 u0 = *(const float4*)(p + 0);
    float4 u1 = *(const float4*)(p + 4);
    float4 u2 = *(const float4*)(p + 8);
    float4 u3 = *(const float4*)(p + 12);
    const int k0 = c * 32;
    const bf16x8 gb0 = *(const bf16x8*)&Wth[(size_t)yoff + srow * 128 + k0 + kc];
    const bf16x8 gb1 = *(const bf16x8*)&Wth[(size_t)yoff + srow * 128 + k0 + kc + 8];
    float xs[16] = {u0.x,u0.y,u0.z,u0.w, u1.x,u1.y,u1.z,u1.w,
                    u2.x,u2.y,u2.z,u2.w, u3.x,u3.y,u3.z,u3.w};
    bf16x8 vh0, vh1;
#pragma unroll
    for (int j = 0; j < 8; j++) vh0[j] = f2bf(xs[j]);
#pragma unroll
    for (int j = 0; j < 8; j++) vh1[j] = f2bf(xs[8 + j]);
    __syncthreads();
    *(bf16x8*)&Ah_s[srow * AP + kc] = vh0;
    *(bf16x8*)&Ah_s[srow * AP + kc + 8] = vh1;
    *(bf16x8*)&Bh_s[srow * AP + kc] = gb0;
    *(bf16x8*)&Bh_s[srow * AP + kc + 8] = gb1;
    __syncthreads();
#pragma unroll
    for (int mt = 0; mt < 8; mt++) {
      const int ar = (mt * 16 + ml) * AP + ko;
      bf16x8 ah = *(const bf16x8*)&Ah_s[ar];
#pragma unroll
      for (int nt = 0; nt < 2; nt++) {
        const int br = (wave * 32 + nt * 16 + ml) * AP + ko;
        bf16x8 bh = *(const bf16x8*)&Bh_s[br];
        acc[nt][mt] = __builtin_amdgcn_mfma_f32_16x16x32_bf16(ah, bh, acc[nt][mt], 0, 0, 0);
      }
    }
  }
  if (blockIdx.y == 0) {
#pragma unroll
    for (int nt = 0; nt < 2; nt++) {
      const int ch = wave * 32 + nt * 16 + ml;
#pragma unroll
      for (int mt = 0; mt < 8; mt++) {
#pragma unroll
        for (int q = 0; q < 4; q++) {
          int nd = nBase + mt * 16 + quad * 4 + q;
          if (nd < Nn) {
            int pk = __builtin_amdgcn_cvt_pk_fp8_f32(acc[nt][mt][q], acc[nt][mt][q], 0, false);
            hs8[(size_t)nd * 128 + ch] = (unsigned char)(pk & 0xff);
          }
        }
      }
    }
  } else {
#pragma unroll
    for (int nt = 0; nt < 2; nt++) {
      const int ch = wave * 32 + nt * 16 + ml;
#pragma unroll
      for (int mt = 0; mt < 8; mt++) {
#pragma unroll
        for (int q = 0; q < 4; q++) {
          int nd = nBase + mt * 16 + quad * 4 + q;
          if (nd < Nn) hdbf[(size_t)nd * 128 + ch] = (unsigned short)f2bf(acc[nt][mt][q]);
        }
      }
    }
  }
}

// ---------------------------------------------------------------- edge pass / aggregation
__global__ __launch_bounds__(256) void agg_kernel(
    const unsigned char* __restrict__ hs8, const unsigned short* __restrict__ hdbf,
    unsigned short* __restrict__ aggbf, const int2* __restrict__ rec,
    const int* __restrict__ rowptr, const float* __restrict__ invdeg,
    const float* __restrict__ Wm, const float* __restrict__ bm) {
  int t = threadIdx.x;
  int hw = t >> 5, lane = t & 31;
  int v = blockIdx.x * 8 + hw;
  if (v >= Nn) return;
  int c0 = lane * 4;
  const float4 We0 = *(const float4*)&Wm[(size_t)256 * 128 + c0];
  const float4 We1 = *(const float4*)&Wm[(size_t)257 * 128 + c0];
  const float4 We2 = *(const float4*)&Wm[(size_t)258 * 128 + c0];
  const float4 b4  = *(const float4*)&bm[c0];
  const ushort4 hd4 = *(const ushort4*)&hdbf[(size_t)v * 128 + c0];
  const float bx = b4.x + bf2f((short)hd4.x), by = b4.y + bf2f((short)hd4.y),
              bz = b4.z + bf2f((short)hd4.z), bw = b4.w + bf2f((short)hd4.w);
  float ax = 0.f, ay = 0.f, az = 0.f, aw = 0.f;
  float ax2 = 0.f, ay2 = 0.f, az2 = 0.f, aw2 = 0.f;
  const int r0 = rowptr[v], r1 = rowptr[v + 1];
  int e = r0;
  for (; e + 2 <= r1; e += 2) {
    int2 q0 = rec[e], q1 = rec[e + 1];
    int s0 = q0.x & 0xffff, s1 = q1.x & 0xffff;
    unsigned hr0 = *(const unsigned*)&hs8[(size_t)s0 * 128 + c0];
    unsigned hr1 = *(const unsigned*)&hs8[(size_t)s1 * 128 + c0];
    float e00 = bf2f((short)(q0.x >> 16));
    float e01 = bf2f((short)(q0.y & 0xffff));
    float e02 = bf2f((short)(q0.y >> 16));
    float e10 = bf2f((short)(q1.x >> 16));
    float e11 = bf2f((short)(q1.y & 0xffff));
    float e12 = bf2f((short)(q1.y >> 16));
    float h0x = __builtin_amdgcn_cvt_f32_fp8(hr0, 0);
    float h0y = __builtin_amdgcn_cvt_f32_fp8(hr0, 1);
    float h0z = __builtin_amdgcn_cvt_f32_fp8(hr0, 2);
    float h0w = __builtin_amdgcn_cvt_f32_fp8(hr0, 3);
    float h1x = __builtin_amdgcn_cvt_f32_fp8(hr1, 0);
    float h1y = __builtin_amdgcn_cvt_f32_fp8(hr1, 1);
    float h1z = __builtin_amdgcn_cvt_f32_fp8(hr1, 2);
    float h1w = __builtin_amdgcn_cvt_f32_fp8(hr1, 3);
    ax += fmaxf(fmaf(e00, We0.x, fmaf(e01, We1.x, fmaf(e02, We2.x, h0x + bx))), 0.f);
    ay += fmaxf(fmaf(e00, We0.y, fmaf(e01, We1.y, fmaf(e02, We2.y, h0y + by))), 0.f);
    az += fmaxf(fmaf(e00, We0.z, fmaf(e01, We1.z, fmaf(e02, We2.z, h0z + bz))), 0.f);
    aw += fmaxf(fmaf(e00, We0.w, fmaf(e01, We1.w, fmaf(e02, We2.w, h0w + bw))), 0.f);
    ax2 += fmaxf(fmaf(e10, We0.x, fmaf(e11, We1.x, fmaf(e12, We2.x, h1x + bx))), 0.f);
    ay2 += fmaxf(fmaf(e10, We0.y, fmaf(e11, We1.y, fmaf(e12, We2.y, h1y + by))), 0.f);
    az2 += fmaxf(fmaf(e10, We0.z, fmaf(e11, We1.z, fmaf(e12, We2.z, h1z + bz))), 0.f);
    aw2 += fmaxf(fmaf(e10, We0.w, fmaf(e11, We1.w, fmaf(e12, We2.w, h1w + bw))), 0.f);
  }
  if (e < r1) {
    int2 q0 = rec[e];
    int s0 = q0.x & 0xffff;
    unsigned hr0 = *(const unsigned*)&hs8[(size_t)s0 * 128 + c0];
    float e00 = bf2f((short)(q0.x >> 16));
    float e01 = bf2f((short)(q0.y & 0xffff));
    float e02 = bf2f((short)(q0.y >> 16));
    float h0x = __builtin_amdgcn_cvt_f32_fp8(hr0, 0);
    float h0y = __builtin_amdgcn_cvt_f32_fp8(hr0, 1);
    float h0z = __builtin_amdgcn_cvt_f32_fp8(hr0, 2);
    float h0w = __builtin_amdgcn_cvt_f32_fp8(hr0, 3);
    ax += fmaxf(fmaf(e00, We0.x, fmaf(e01, We1.x, fmaf(e02, We2.x, h0x + bx))), 0.f);
    ay += fmaxf(fmaf(e00, We0.y, fmaf(e01, We1.y, fmaf(e02, We2.y, h0y + by))), 0.f);
    az += fmaxf(fmaf(e00, We0.z, fmaf(e01, We1.z, fmaf(e02, We2.z, h0z + bz))), 0.f);
    aw += fmaxf(fmaf(e00, We0.w, fmaf(e01, We1.w, fmaf(e02, We2.w, h0w + bw))), 0.f);
  }
  const float idg = invdeg[v];
  ushort4 o;
  o.x = (unsigned short)f2bf((ax + ax2) * idg);
  o.y = (unsigned short)f2bf((ay + ay2) * idg);
  o.z = (unsigned short)f2bf((az + az2) * idg);
  o.w = (unsigned short)f2bf((aw + aw2) * idg);
  *(ushort4*)&aggbf[(size_t)v * 128 + c0] = o;
}

// ---------------------------------------------------------------- update (MFMA split-bf16) + fused group-sum
__global__ __launch_bounds__(256) void updg_mfma(
    float* __restrict__ h, const unsigned short* __restrict__ aggbf,
    const int* __restrict__ batch,
    const short* __restrict__ Wth, const short* __restrict__ Wtl,
    const float* __restrict__ gb, float* __restrict__ gsum_out) {
  __shared__ short Ah_s[128 * AP], Al_s[128 * AP];
  __shared__ short Bh_s[128 * AP], Bl_s[128 * AP];
  __shared__ float gbs[Bb * 128];
  __shared__ float ls[Bb * 128];
  const int t = threadIdx.x;
  const int nBase = blockIdx.x * 128;
  *(float4*)&gbs[t * 4] = *(const float4*)&gb[t * 4];
#pragma unroll
  for (int q = 0; q < 4; q++) ls[t + q * 256] = 0.f;

  const int wave = t >> 6, lane = t & 63;
  const int ml = lane & 15, quad = lane >> 4;
  const int ko = quad * 8;

  f32x4 acc[2][8];
#pragma unroll
  for (int nt = 0; nt < 2; nt++)
#pragma unroll
    for (int mt = 0; mt < 8; mt++)
#pragma unroll
      for (int q = 0; q < 4; q++) acc[nt][mt][q] = 0.f;

  const int srow = t >> 1;
  const int kc = (t & 1) * 16;
  const int nd0 = nBase + srow;
  const int nn = nd0 < Nn ? nd0 : Nn - 1;

  for (int c = 0; c < 8; c++) {
    const int k0 = c * 32;
    bf16x8 vh0, vh1, vl0, vl1;
    if (c < 4) {
      const float* p = &h[(size_t)nn * 128 + c * 32 + kc];
      float4 u0 = *(const float4*)(p + 0);
      float4 u1 = *(const float4*)(p + 4);
      float4 u2 = *(const float4*)(p + 8);
      float4 u3 = *(const float4*)(p + 12);
      float xs[16] = {u0.x,u0.y,u0.z,u0.w, u1.x,u1.y,u1.z,u1.w,
                      u2.x,u2.y,u2.z,u2.w, u3.x,u3.y,u3.z,u3.w};
#pragma unroll
      for (int j = 0; j < 8; j++) {
        short hi = f2bf(xs[j]);
        vh0[j] = hi; vl0[j] = f2bf(xs[j] - bf2f(hi));
      }
#pragma unroll
      for (int j = 0; j < 8; j++) {
        short hi = f2bf(xs[8 + j]);
        vh1[j] = hi; vl1[j] = f2bf(xs[8 + j] - bf2f(hi));
      }
    } else {
      const unsigned short* pa = &aggbf[(size_t)nn * 128 + (c - 4) * 32 + kc];
      vh0 = *(const bf16x8*)(pa);
      vh1 = *(const bf16x8*)(pa + 8);
    }
    const bf16x8 gb0 = *(const bf16x8*)&Wth[(size_t)srow * 256 + k0 + kc];
    const bf16x8 gb1 = *(const bf16x8*)&Wth[(size_t)srow * 256 + k0 + kc + 8];
    const bf16x8 gl0 = *(const bf16x8*)&Wtl[(size_t)srow * 256 + k0 + kc];
    const bf16x8 gl1 = *(const bf16x8*)&Wtl[(size_t)srow * 256 + k0 + kc + 8];
    __syncthreads();
    *(bf16x8*)&Ah_s[srow * AP + kc] = vh0;
    *(bf16x8*)&Ah_s[srow * AP + kc + 8] = vh1;
    if (c < 4) {
      *(bf16x8*)&Al_s[srow * AP + kc] = vl0;
      *(bf16x8*)&Al_s[srow * AP + kc + 8] = vl1;
    }
    *(bf16x8*)&Bh_s[srow * AP + kc] = gb0;
    *(bf16x8*)&Bh_s[srow * AP + kc + 8] = gb1;
    *(bf16x8*)&Bl_s[srow * AP + kc] = gl0;
    *(bf16x8*)&Bl_s[srow * AP + kc + 8] = gl1;
    __syncthreads();
    if (c < 4) {
#pragma unroll
      for (int mt = 0; mt < 8; mt++) {
        const int ar = (mt * 16 + ml) * AP + ko;
        bf16x8 ah = *(const bf16x8*)&Ah_s[ar];
        bf16x8 al = *(const bf16x8*)&Al_s[ar];
#pragma unroll
        for (int nt = 0; nt < 2; nt++) {
          const int br = (wave * 32 + nt * 16 + ml) * AP + ko;
          bf16x8 bh = *(const bf16x8*)&Bh_s[br];
          bf16x8 bl = *(const bf16x8*)&Bl_s[br];
          acc[nt][mt] = __builtin_amdgcn_mfma_f32_16x16x32_bf16(ah, bh, acc[nt][mt], 0, 0, 0);
          acc[nt][mt] = __builtin_amdgcn_mfma_f32_16x16x32_bf16(ah, bl, acc[nt][mt], 0, 0, 0);
          acc[nt][mt] = __builtin_amdgcn_mfma_f32_16x16x32_bf16(al, bh, acc[nt][mt], 0, 0, 0);
        }
      }
    } else {
#pragma unroll
      for (int mt = 0; mt < 8; mt++) {
        const int ar = (mt * 16 + ml) * AP + ko;
        bf16x8 ah = *(const bf16x8*)&Ah_s[ar];
#pragma unroll
        for (int nt = 0; nt < 2; nt++) {
          const int br = (wave * 32 + nt * 16 + ml) * AP + ko;
          bf16x8 bh = *(const bf16x8*)&Bh_s[br];
          bf16x8 bl = *(const bf16x8*)&Bl_s[br];
          acc[nt][mt] = __builtin_amdgcn_mfma_f32_16x16x32_bf16(ah, bh, acc[nt][mt], 0, 0, 0);
          acc[nt][mt] = __builtin_amdgcn_mfma_f32_16x16x32_bf16(ah, bl, acc[nt][mt], 0, 0, 0);
        }
      }
    }
  }
#pragma unroll
  for (int nt = 0; nt < 2; nt++) {
    const int ch = wave * 32 + nt * 16 + ml;
#pragma unroll
    for (int mt = 0; mt < 8; mt++) {
      int rbase = nBase + mt * 16 + quad * 4;
      float runv = 0.f;
      int curb = -1;
#pragma unroll
      for (int q = 0; q < 4; q++) {
        int nd = rbase + q;
        if (nd < Nn) {
          int bi = batch[nd];
          float u = fmaxf(acc[nt][mt][q] + gbs[bi * 128 + ch], 0.f);
          float hn = h[(size_t)nd * 128 + ch] + u;
          h[(size_t)nd * 128 + ch] = hn;
          if (bi != curb) {
            if (curb >= 0) atomicAdd(&ls[curb * 128 + ch], runv);
            curb = bi;
            runv = 0.f;
          }
          runv += hn;
        }
      }
      if (curb >= 0) atomicAdd(&ls[curb * 128 + ch], runv);
    }
  }
  __syncthreads();
#pragma unroll
  for (int q = 0; q < 4; q++) {
    int idx = t + q * 256;
    float v = ls[idx];
    if (v != 0.f) atomicAdd(&gsum_out[idx], v);
  }
}

// ---------------------------------------------------------------- kwv (MFMA bf16) + fused decode
// decode split 2-way: all 256 threads compute 64-k partials into dsum; the
// previous tile's outputs are combined after the next tile's first barrier.
__global__ __launch_bounds__(256) void kwv_kernel(
    const float* __restrict__ h, const float* __restrict__ pos,
    const float* __restrict__ Fm, const float* __restrict__ Wd,
    const float* __restrict__ bd, float* __restrict__ partial,
    float* __restrict__ ksum, float* __restrict__ out) {
  __shared__ float h_s[32 * HP];     // fp32 tile for decode
  __shared__ short nkT[128 * KS];    // A: nkT[m][k]
  __shared__ short hT[128 * KS];     // B: hT[n][k]
  __shared__ float wd[512];
  __shared__ float ksum_s[128];
  __shared__ float dsum[256];
  const int t = threadIdx.x;
  const int hr = t >> 3;
  const int hc = (t & 7) * 16;
  const int fg = (t & 7) * 8;
  const int wave = t >> 6, lane = t & 63;
  const int ml = lane & 15, quad = lane >> 4;
  const int ko = quad * 8;
  if (t < 128) { *(float4*)&wd[t * 4] = *(const float4*)&Wd[t * 4]; ksum_s[t] = 0.f; }
  const float bdv = bd[t & 3];
  const int dn = (t & 127) >> 2, dno = t & 3;     // decode output (node-in-tile, out)
  const int dk0 = (t >> 7) * 64;                  // decode k half
  f32x4 acc[2][8];
#pragma unroll
  for (int nt = 0; nt < 2; nt++)
#pragma unroll
    for (int mt = 0; mt < 8; mt++)
#pragma unroll
      for (int q = 0; q < 4; q++) acc[nt][mt][q] = 0.f;
  float klc[8], kls[8];
#pragma unroll
  for (int f = 0; f < 8; f++) { klc[f] = 0.f; kls[f] = 0.f; }

  int ptile = -1;
  const int nTiles = (Nn + 31) / 32;  // 1563
  for (int tile = blockIdx.x; tile < nTiles; tile += gridDim.x) {
    const int gh = tile * 32 + hr;
    float4 hv0 = {0.f, 0.f, 0.f, 0.f}, hv1 = hv0, hv2 = hv0, hv3 = hv0;
    float cbuf[8], sbuf[8];
    if (gh < Nn) {
      const float* hp = &h[(size_t)gh * 128 + hc];
      hv0 = *(const float4*)(hp + 0);
      hv1 = *(const float4*)(hp + 4);
      hv2 = *(const float4*)(hp + 8);
      hv3 = *(const float4*)(hp + 12);
      const float px = pos[gh * 2 + 0], py = pos[gh * 2 + 1];
#pragma unroll
      for (int f = 0; f < 8; f++) {
        float p = px * Fm[fg + f] + py * Fm[64 + fg + f];
        cbuf[f] = cosf(p) * 0.125f;
        sbuf[f] = sinf(p) * 0.125f;
      }
    } else {
#pragma unroll
      for (int f = 0; f < 8; f++) { cbuf[f] = 0.f; sbuf[f] = 0.f; }
    }
    float xs[16] = {hv0.x,hv0.y,hv0.z,hv0.w, hv1.x,hv1.y,hv1.z,hv1.w,
                    hv2.x,hv2.y,hv2.z,hv2.w, hv3.x,hv3.y,hv3.z,hv3.w};
    __syncthreads();  // prev tile's LDS reads & dsum writes done
    if (ptile >= 0 && t < 128) {
      int gn = ptile * 32 + dn;
      if (gn < Nn) out[4 + (size_t)gn * 4 + dno] = dsum[t] + dsum[t + 128] + bdv;
    }
    *(float4*)&h_s[hr * HP + hc + 0]  = hv0;
    *(float4*)&h_s[hr * HP + hc + 4]  = hv1;
    *(float4*)&h_s[hr * HP + hc + 8]  = hv2;
    *(float4*)&h_s[hr * HP + hc + 12] = hv3;
#pragma unroll
    for (int i = 0; i < 16; i++) hT[(hc + i) * KS + hr] = f2bf(xs[i]);
#pragma unroll
    for (int f = 0; f < 8; f++) {
      nkT[(fg + f) * KS + hr] = f2bf(cbuf[f]);
      nkT[(64 + fg + f) * KS + hr] = f2bf(sbuf[f]);
      klc[f] += cbuf[f];
      kls[f] += sbuf[f];
    }
    __syncthreads();
#pragma unroll
    for (int mt = 0; mt < 8; mt++) {
      bf16x8 ah = *(const bf16x8*)&nkT[(mt * 16 + ml) * KS + ko];
#pragma unroll
      for (int nt = 0; nt < 2; nt++) {
        bf16x8 bh = *(const bf16x8*)&hT[(wave * 32 + nt * 16 + ml) * KS + ko];
        acc[nt][mt] = __builtin_amdgcn_mfma_f32_16x16x32_bf16(ah, bh, acc[nt][mt], 0, 0, 0);
      }
    }
    {  // decode partial: 64-deep half-loop on all 256 threads
      float s = 0.f;
#pragma unroll 4
      for (int kk = dk0; kk < dk0 + 64; kk++) {
        int k = (kk + dn) & 127;
        s = fmaf(h_s[dn * HP + k], wd[k * 4 + dno], s);
      }
      dsum[t] = s;
    }
    ptile = tile;
  }
  __syncthreads();
  if (ptile >= 0 && t < 128) {  // drain last tile
    int gn = ptile * 32 + dn;
    if (gn < Nn) out[4 + (size_t)gn * 4 + dno] = dsum[t] + dsum[t + 128] + bdv;
  }
  float* pb = &partial[(size_t)blockIdx.x * 16384];
#pragma unroll
  for (int nt = 0; nt < 2; nt++) {
    const int col = wave * 32 + nt * 16 + ml;
#pragma unroll
    for (int mt = 0; mt < 8; mt++) {
#pragma unroll
      for (int q = 0; q < 4; q++) {
        int row = mt * 16 + quad * 4 + q;
        pb[row * 128 + col] = acc[nt][mt][q];
      }
    }
  }
#pragma unroll
  for (int f = 0; f < 8; f++) {
    atomicAdd(&ksum_s[fg + f], klc[f]);
    atomicAdd(&ksum_s[64 + fg + f], kls[f]);
  }
  __syncthreads();
  if (t < 128) atomicAdd(&ksum[t], ksum_s[t]);
}

__global__ __launch_bounds__(256) void kwv_reduce(const float* __restrict__ partial,
                                                  float* __restrict__ kwv) {
  int idx = blockIdx.x * 256 + threadIdx.x;
  float s = 0.f;
  for (int b = 0; b < KWVB; b++) s += partial[(size_t)b * 16384 + idx];
  kwv[idx] = s;
}

// ---------------------------------------------------------------- final sampling head
__global__ __launch_bounds__(128) void final_kernel(
    const float* __restrict__ sp, const float* __restrict__ Fm,
    const float* __restrict__ kwv, const float* __restrict__ vs,
    const float* __restrict__ ksum, const float* __restrict__ Wd,
    const float* __restrict__ bd, float* __restrict__ out) {
  __shared__ float nq_s[128];
  __shared__ float red[2];
  __shared__ float redU[8];
  int t = threadIdx.x;
  int jj = t & 63;
  float p = sp[0] * Fm[jj] + sp[1] * Fm[64 + jj];
  nq_s[t] = ((t < 64) ? cosf(p) : sinf(p)) * 0.125f;  // ||q||=sqrt(0.5) exact
  __syncthreads();
  float num = 0.f;
#pragma unroll
  for (int g = 0; g < Bb; g++) num += vs[g * 128 + t];
  for (int k = 0; k < 128; k++) num = fmaf(nq_s[k], kwv[k * 128 + t], num);
  float dp = nq_s[t] * ksum[t];
#pragma unroll
  for (int off = 32; off > 0; off >>= 1) dp += __shfl_down(dp, off);
  if ((t & 63) == 0) red[t >> 6] = dp;
  __syncthreads();
  float den = (float)Nn + red[0] + red[1];
  float e = num / den;
  float u[4];
#pragma unroll
  for (int o = 0; o < 4; o++) u[o] = e * Wd[t * 4 + o];
#pragma unroll
  for (int off = 32; off > 0; off >>= 1) {
#pragma unroll
    for (int o = 0; o < 4; o++) u[o] += __shfl_down(u[o], off);
  }
  if ((t & 63) == 0) {
#pragma unroll
    for (int o = 0; o < 4; o++) redU[(t >> 6) * 4 + o] = u[o];
  }
  __syncthreads();
  if (t < 4) out[t] = redU[t] + redU[4 + t] + bd[t];
}

// ---------------------------------------------------------------- launcher
extern "C" void kernel_launch(void* const* d_in, const int* in_sizes, int n_in,
                              void* d_out, int out_size, void* d_ws, size_t ws_size,
                              hipStream_t stream) {
  const float* x    = (const float*)d_in[0];
  const float* xm   = (const float*)d_in[1];
  const int*   ei   = (const int*)d_in[2];
  const float* ea   = (const float*)d_in[3];
  const float* pos  = (const float*)d_in[4];
  const int*   batch= (const int*)d_in[5];
  const float* sp   = (const float*)d_in[6];
  const float* Fm   = (const float*)d_in[7];
  const float* Wenc = (const float*)d_in[8];
  const float* benc = (const float*)d_in[9];
  const float* Wmsg = (const float*)d_in[10];
  const float* bmsg = (const float*)d_in[11];
  const float* Wupd = (const float*)d_in[12];
  const float* bupd = (const float*)d_in[13];
  const float* Wdec = (const float*)d_in[14];
  const float* bdec = (const float*)d_in[15];
  float* out = (float*)d_out;

  float* ws     = (float*)d_ws;
  float* h      = ws;                              // N*128
  float* agg    = h + (size_t)Nn * 128;            // region: aggbf (12.8MB); kwv partials span
  float* aux    = agg + (size_t)Nn * 128;          // region: hs8 (6.4MB) + hdbf (12.8MB)
  float* invdeg = aux + (size_t)Nn * 128;          // N
  // ---- zeroed region (6416 floats) ----
  float* gsum   = invdeg + Nn;                     // 1024
  float* gcnt   = gsum + 1024;                     // 8
  float* bcsum  = gcnt + 8;                        // 1024
  float* bccnt  = bcsum + 1024;                    // 8
  float* gsumR  = bccnt + 8;                       // 4*1024
  float* vsum   = gsumR + 4096;                    // 128 (unused)
  float* ksum   = vsum + 128;                      // 128
  // ---- end zeroed region ----
  float* gbst   = ksum + 128;                      // 1024
  float* gbuf   = gbst + 1024;                     // 4*1024
  float* kwv    = gbuf + 4096;                     // 16384
  int2*  rec    = (int2*)(kwv + 16384);            // E (packed 8B, CSR order)
  int*   cnt    = (int*)(rec + Ee);                // N
  int*   rowptr = cnt + Nn;                        // N+1
  int*   bsum   = rowptr + Nn + 1;                 // 256
  int*   boff   = bsum + 256;                      // 256
  int*   bktcnt = boff + 256;                      // 196 (zeroed)
  int*   bktbase= bktcnt + 196;                    // 197
  int*   bktcur = bktbase + 197;                   // 196
  short* wmt_h  = (short*)(bktcur + 196);          // 2*128*128
  short* wmt_l  = wmt_h + 32768;
  short* wut_h  = wmt_l + 32768;                   // 128*256
  short* wut_l  = wut_h + 32768;
  int2*  recA   = (int2*)(wut_l + 32768);          // E (bucket-partitioned staging)
  unsigned char* dlo = (unsigned char*)(recA + Ee);// E

  unsigned short* aggbf = (unsigned short*)agg;                     // 12.8 MB
  unsigned char*  hs8   = (unsigned char*)aux;                      // 6.4 MB
  unsigned short* hdbf  = (unsigned short*)(hs8 + (size_t)Nn * 128);// 12.8 MB

  hipMemsetAsync(gsum, 0, 6416 * sizeof(float), stream);
  hipMemsetAsync(bktcnt, 0, 196 * sizeof(int), stream);

  split_w_kernel<<<256, 256, 0, stream>>>(Wmsg, Wupd, wmt_h, wmt_l, wut_h, wut_l);

  // CSR build via 2-phase radix partition (all passes coalesced)
  bkt_cnt<<<P1B, 256, 0, stream>>>(ei, bktcnt);
  bkt_scan<<<1, 256, 0, stream>>>(bktcnt, bktbase, bktcur);
  bkt_part<<<P1B, 256, 0, stream>>>(ei, ea, bktcur, recA, dlo);
  dst_cnt<<<NBK, 256, 0, stream>>>(bktbase, dlo, cnt);
  bsum_kernel<<<SCB, 256, 0, stream>>>(cnt, bsum);
  scan_top_kernel<<<1, 256, 0, stream>>>(bsum, boff);
  apply_kernel<<<SCB, 256, 0, stream>>>(cnt, boff, rowptr, invdeg);
  bkt_fin<<<NBK, 256, 0, stream>>>(bktbase, recA, dlo, rowptr, rec);

  const int nb128 = (Nn + 127) / 128;  // 391
  encode_seg<<<nb128, 256, 0, stream>>>(x, xm, batch, Wenc, benc, h,
                                        gsum, gcnt, bcsum, bccnt);
  gb_static_kernel<<<Bb, 128, 0, stream>>>(bcsum, bccnt, Wupd, bupd, gbst);
  gb_dyn_kernel<<<Bb, 128, 0, stream>>>(gsum, gcnt, gbst, Wupd, gbuf);

  for (int r = 0; r < ROUNDS; r++) {
    proj_mfma<<<dim3(nb128, 2), 256, 0, stream>>>(h, wmt_h, hs8, hdbf);
    agg_kernel<<<(Nn + 7) / 8, 256, 0, stream>>>(hs8, hdbf, aggbf, rec, rowptr,
                                                 invdeg, Wmsg, bmsg);
    updg_mfma<<<nb128, 256, 0, stream>>>(h, aggbf, batch, wut_h, wut_l,
                                         gbuf + r * 1024, gsumR + r * 1024);
    if (r < ROUNDS - 1)
      gb_dyn_kernel<<<Bb, 128, 0, stream>>>(gsumR + r * 1024, gcnt, gbst, Wupd,
                                            gbuf + (r + 1) * 1024);
  }

  // kwv partials alias the (now free) agg+aux regions: 512*64KB = 33.5 MB < 51.2 MB
  kwv_kernel<<<KWVB, 256, 0, stream>>>(h, pos, Fm, Wdec, bdec, agg, ksum, out);
  kwv_reduce<<<64, 256, 0, stream>>>(agg, kwv);
  final_kernel<<<1, 128, 0, stream>>>(sp, Fm, kwv, gsumR + 3 * 1024, ksum,
                                      Wdec, bdec, out);
}